// Round 14
// baseline (414.847 us; speedup 1.0000x reference)
//
#include <hip/hip_runtime.h>

typedef _Float16 v8h __attribute__((ext_vector_type(8)));
typedef _Float16 v4h __attribute__((ext_vector_type(4)));
typedef float    v4f __attribute__((ext_vector_type(4)));

template<int V> struct IC { static constexpr int value = V; };

__device__ __forceinline__ float fast_tanh(float x) {
    float e = __expf(2.0f * x);
    return 1.0f - 2.0f / (e + 1.0f);
}

// ---------------------------------------------------------------------------
// pack layout (halves), unchanged:
//  hidden: idx = ((((pipe*3+l)*8 + nt)*4 + kk)*64 + lane)*8 + j     [0, 98304)
//  L0 (legacy, unused):                                             [98304, 106496)
//  wout A-fragments: 106496 + ((pipe*4 + kk)*64 + lane)*8 + j       [106496, 110592)
// ---------------------------------------------------------------------------
__global__ void pack_weights(const float* __restrict__ dpWh,
                             const float* __restrict__ icWh,
                             const float* __restrict__ dpWin,
                             const float* __restrict__ icWin,
                             const float* __restrict__ dpWout,
                             const float* __restrict__ icWout,
                             _Float16* __restrict__ out) {
    int idx = blockIdx.x * 256 + threadIdx.x;
    if (idx < 98304) {
        int j    = idx & 7;
        int lane = (idx >> 3) & 63;
        int kk   = (idx >> 9) & 3;
        int nt   = (idx >> 11) & 7;
        int lp   = idx >> 14;           // 0..5
        int l    = lp % 3;
        const float* src = (lp >= 3) ? icWh : dpWh;
        int k = kk * 32 + (lane >> 4) * 8 + j;
        int n = nt * 16 + (lane & 15);
        out[idx] = (_Float16)src[(l * 128 + k) * 128 + n];
    } else if (idx < 106496) {
        int f    = idx - 98304;
        int j    = f & 7;
        int lane = (f >> 3) & 63;
        int nt   = (f >> 9) & 7;
        int pipe = (f >> 12) & 1;
        int k = (lane >> 4) * 8 + j;
        int n = nt * 16 + (lane & 15);
        float v = 0.0f;
        if (pipe == 0) { if (k < 4) v = dpWin[k * 128 + n]; }
        else           { if (k < 3) v = icWin[k * 128 + n]; }
        out[idx] = (_Float16)v;
    } else if (idx < 110592) {
        int f    = idx - 106496;
        int j    = f & 7;
        int lane = (f >> 3) & 63;
        int kk   = (f >> 9) & 3;
        int pipe = (f >> 11) & 1;
        float v = 0.0f;
        if ((lane & 15) == 0)
            v = (pipe ? icWout : dpWout)[kk * 32 + (lane >> 4) * 8 + j];
        out[idx] = (_Float16)v;
    }
}

// LDS (dynamic, 150528 B -> 1 block/CU, 8 waves = 2/SIMD):
//   [0,     69632)  act0 : 256 vrows x ROWH halves (vrow = set*64 + st*16 + phys)
//   [69632,139264)  act1
//   [139264,143360) btab : f32[8][128]  0=dpBin 1..3=dpBh 4=icBin 5..7=icBh
//   [143360,147456) winb : f32[8][128]  0..3=dpWin k, 4..6=icWin k, 7=0
//   [147456,148480) cbuf : f32[256]
//   [148480,150528) rowb : f32[2][16][16] geometry, ping-pong by batch parity
#define ROWH 136
#define ABUFH (256 * ROWH)
#define SMEM_BYTES 150528

// Wave grid 2x4: rg = vrow half (128 rows), cg = 32-feature slice.
// Halves the act LDS re-read (the measured r13 bottleneck: LDS pipe ~85% busy).
__launch_bounds__(512, 2)
__global__ void node_main(const float* __restrict__ tx,
                          const float* __restrict__ dpBin, const float* __restrict__ dpBh,
                          const float* __restrict__ icBin, const float* __restrict__ icBh,
                          const float* __restrict__ dpWin, const float* __restrict__ icWin,
                          const float* __restrict__ dpBout, const float* __restrict__ icBout,
                          const _Float16* __restrict__ pack,
                          float* __restrict__ outPot, float* __restrict__ outAcc,
                          int N)
{
    extern __shared__ char smem[];
    _Float16* act0 = (_Float16*)smem;
    _Float16* act1 = act0 + ABUFH;
    float* btab = (float*)(smem + 139264);
    float* winb = (float*)(smem + 143360);
    float* cbuf = (float*)(smem + 147456);
    float* rowb = (float*)(smem + 148480);

    const int tid  = threadIdx.x;
    const int wave = tid >> 6;
    const int lane = tid & 63;
    const int l15  = lane & 15;
    const int s    = lane >> 4;
    const int rg   = wave >> 2;         // vrow half: rows rg*128 .. rg*128+127
    const int cg   = wave & 3;          // 32-feature slice
    const int fb   = cg * 32 + s * 4;   // sub-slice 0 feature base
    const int f8   = cg * 32 + s * 8;   // L0: 8 features per thread

    // ---- stage bias + input-layer weight tables ----
    for (int i = tid; i < 1024; i += 512) {
        int row = i >> 7, col = i & 127;
        float bv, wv;
        if      (row == 0) bv = dpBin[col];
        else if (row <  4) bv = dpBh[(row - 1) * 128 + col];
        else if (row == 4) bv = icBin[col];
        else               bv = icBh[(row - 5) * 128 + col];
        if      (row <  4) wv = dpWin[row * 128 + col];
        else if (row <  7) wv = icWin[(row - 4) * 128 + col];
        else               wv = 0.0f;
        btab[i] = bv;
        winb[i] = wv;
    }

    // ---- persistent dp weights for my 32-feature slice (96 regs) ----
    v8h wreg[3][2][4];
    #pragma unroll
    for (int L = 0; L < 3; L++)
        #pragma unroll
        for (int n2 = 0; n2 < 2; n2++)
            #pragma unroll
            for (int kk = 0; kk < 4; kk++)
                wreg[L][n2][kk] = *(const v8h*)(pack + (((L * 8 + cg * 2 + n2) * 4 + kk) << 9) + (lane << 3));

    // persistent wout A-fragments (16 regs)
    v8h wof[4];
    {
        const _Float16* wsf = pack + 106496 + ((wave >= 6) ? 2048 : 0) + (lane << 3);
        #pragma unroll
        for (int kk = 0; kk < 4; kk++)
            wof[kk] = *(const v8h*)(wsf + (kk << 9));
    }

    const float boutd = dpBout[0];
    const float bouti = icBout[0];
    __syncthreads();

    // ---- static LDS bases (wave's own 128-row half) ----
    _Float16* ep0 = act0 + (rg * 128 + l15) * ROWH + fb;
    _Float16* ep1 = act1 + (rg * 128 + l15) * ROWH + fb;
    const _Float16* rd0 = act0 + (rg * 128 + l15) * ROWH + s * 8;
    const _Float16* rd1 = act1 + (rg * 128 + l15) * ROWH + s * 8;
    _Float16* e80 = act0 + (rg * 128 + l15) * ROWH + f8;    // L0 writes (v8h)

    auto epi_p = [&](v4f acc, v4h& Dkh, _Float16* p) {
        float h0 = fast_tanh(acc[0]), h1 = fast_tanh(acc[1]);
        float h2 = fast_tanh(acc[2]), h3 = fast_tanh(acc[3]);
        Dkh[0] = (_Float16)(1.0f - h0 * h0);
        Dkh[1] = (_Float16)(1.0f - h1 * h1);
        Dkh[2] = (_Float16)(1.0f - h2 * h2);
        Dkh[3] = (_Float16)(1.0f - h3 * h3);
        v4h w = {(_Float16)h0, (_Float16)h1, (_Float16)h2, (_Float16)h3};
        *(v4h*)p = w;
    };
    auto epi_t = [&](v4f acc, const v4h& Dkh, _Float16* p) {
        v4h av = {(_Float16)acc[0], (_Float16)acc[1],
                  (_Float16)acc[2], (_Float16)acc[3]};
        *(v4h*)p = av * Dkh;                            // pk_mul
    };

    // 4 tiles of one set: W = weight slice [2 subslices][4 kk], br = bias row
    auto quad = [&](const v8h (&W)[2][4], const float* br,
                    const _Float16* rb, _Float16* wb, int jbase) {
        v4h Dk0, Dk1;
        #pragma unroll
        for (int q = 0; q < 4; q++) {
            const int ro = (jbase + q) * (16 * ROWH);
            v8h b0 = *(const v8h*)(rb + ro);
            v8h b1 = *(const v8h*)(rb + ro + 32);
            v8h b2 = *(const v8h*)(rb + ro + 64);
            v8h b3 = *(const v8h*)(rb + ro + 96);
            v4f a0, a1;
            if (q == 0) { a0 = *(const v4f*)br; a1 = *(const v4f*)(br + 16); }
            else { v4f z = {0.f, 0.f, 0.f, 0.f}; a0 = z; a1 = z; }
            a0 = __builtin_amdgcn_mfma_f32_16x16x32_f16(W[0][0], b0, a0, 0, 0, 0);
            a1 = __builtin_amdgcn_mfma_f32_16x16x32_f16(W[1][0], b0, a1, 0, 0, 0);
            a0 = __builtin_amdgcn_mfma_f32_16x16x32_f16(W[0][1], b1, a0, 0, 0, 0);
            a1 = __builtin_amdgcn_mfma_f32_16x16x32_f16(W[1][1], b1, a1, 0, 0, 0);
            a0 = __builtin_amdgcn_mfma_f32_16x16x32_f16(W[0][2], b2, a0, 0, 0, 0);
            a1 = __builtin_amdgcn_mfma_f32_16x16x32_f16(W[1][2], b2, a1, 0, 0, 0);
            a0 = __builtin_amdgcn_mfma_f32_16x16x32_f16(W[0][3], b3, a0, 0, 0, 0);
            a1 = __builtin_amdgcn_mfma_f32_16x16x32_f16(W[1][3], b3, a1, 0, 0, 0);
            _Float16* p = wb + (jbase + q) * (16 * ROWH);
            if (q == 0) { epi_p(a0, Dk0, p); epi_p(a1, Dk1, p + 16); }
            else        { epi_t(a0, Dk0, p); epi_t(a1, Dk1, p + 16); }
        }
    };

    // one hidden layer over my 8 tiles (2 sets); rg1's second set is ic,
    // whose weight slice streams transiently from L2 (hidden under set A).
    auto hpass = [&](auto Lc, const _Float16* rb, _Float16* wb) {
        constexpr int L = decltype(Lc)::value;
        v8h icw[2][4];
        if (rg) {
            #pragma unroll
            for (int n2 = 0; n2 < 2; n2++)
                #pragma unroll
                for (int kk = 0; kk < 4; kk++)
                    icw[n2][kk] = *(const v8h*)(pack + ((((3 + L) * 8 + cg * 2 + n2) * 4 + kk) << 9) + (lane << 3));
        }
        const float* brdp = btab + (1 + L) * 128 + fb;
        quad(wreg[L], brdp, rb, wb, 0);                      // set A (dp)
        if (rg) quad(icw,     btab + (5 + L) * 128 + fb, rb, wb, 4);  // set 3 (ic)
        else    quad(wreg[L], brdp,                      rb, wb, 4);  // set 1 (dp)
    };

    const float NP0 = 1.0f - 0.7745966692414834f;   // GL node+1
    const float NP2 = 1.0f + 0.7745966692414834f;

    const int nbat = (N + 15) >> 4;
    int par = 0;
    for (int b = blockIdx.x; b < nbat; b += gridDim.x, par ^= 1) {
        // ---- geometry: wave 0 computes, everyone reads (rowb ping-pong) ----
        if (wave == 0 && lane < 16) {
            int prow = b * 16 + lane;
            float4 q = (prow < N) ? ((const float4*)tx)[prow] : make_float4(0.f, 1.f, 1.f, 1.f);
            float t = q.x, x = q.y, y = q.z, z = q.w;
            float r2 = x * x + y * y + z * z;
            float r  = sqrtf(r2 + 1e-12f);
            float rinv = 1.0f / r;
            float uc = fminf(1.0f, fmaxf(-1.0f, z * rinv));
            float th = acosf(uc);
            float ph = atan2f(y, x);
            float rinv3 = rinv * rinv * rinv;
            float dacos = -1.0f / sqrtf(fmaxf(1.0f - uc * uc, 1e-30f));
            float rho2 = fmaxf(x * x + y * y, 1e-30f);
            float opr  = 1.0f + r;
            float den  = r * r + 0.1f;
            float isq  = 1.0f / sqrtf(den);
            float* rbp = rowb + par * 256 + lane * 16;
            rbp[0]  = t;
            rbp[1]  = x * rinv; rbp[2] = y * rinv; rbp[3] = z * rinv;
            rbp[4]  = dacos * (-x * z * rinv3);
            rbp[5]  = dacos * (-y * z * rinv3);
            rbp[6]  = dacos * (rinv - z * z * rinv3);
            rbp[7]  = -y / rho2;
            rbp[8]  =  x / rho2;
            rbp[9]  = -1.0f / opr;
            rbp[10] =  1.0f / (opr * opr);
            rbp[11] = -isq;
            rbp[12] = r * isq * isq * isq;
            rbp[13] = r; rbp[14] = th; rbp[15] = ph;
        }
        __syncthreads();                               // rowb ready

        const float* rbl = rowb + par * 256 + l15 * 16;
        float t = rbl[0], r = rbl[13], th = rbl[14], ph = rbl[15];

        // ---- L0 (fp32 VALU): my 2 sets x 8 features/thread -> act0 ----
        #pragma unroll
        for (int ls = 0; ls < 2; ls++) {
            const int set = rg * 2 + ls;
            const bool icp = (set == 3);
            const float* wb = winb + (icp ? 512 : 0);
            v4f pa = *(const v4f*)(btab + (icp ? 512 : 0) + f8);
            v4f pb = *(const v4f*)(btab + (icp ? 512 : 0) + f8 + 4);
            v4f w0a = *(const v4f*)(wb + f8),       w0b = *(const v4f*)(wb + f8 + 4);
            v4f w1a = *(const v4f*)(wb + 128 + f8), w1b = *(const v4f*)(wb + 128 + f8 + 4);
            v4f w2a = *(const v4f*)(wb + 256 + f8), w2b = *(const v4f*)(wb + 256 + f8 + 4);
            v4f w3a, w3b;
            if (icp) { v4f z = {0.f, 0.f, 0.f, 0.f}; w3a = z; w3b = z; }
            else { w3a = *(const v4f*)(wb + 384 + f8); w3b = *(const v4f*)(wb + 384 + f8 + 4); }
            float i0, i1, i2, i3;
            if (icp) { i0 = r; i1 = th; i2 = ph; i3 = 0.0f; }
            else {
                float np1 = (set == 0) ? NP0 : ((set == 1) ? 1.0f : NP2);
                i0 = 0.5f * t * np1; i1 = r; i2 = th; i3 = ph;
            }
            #pragma unroll
            for (int j = 0; j < 4; j++) {
                pa[j] += i0 * w0a[j] + i1 * w1a[j] + i2 * w2a[j] + i3 * w3a[j];
                pb[j] += i0 * w0b[j] + i1 * w1b[j] + i2 * w2b[j] + i3 * w3b[j];
            }
            float h[8], D[8];
            #pragma unroll
            for (int j = 0; j < 4; j++) {
                h[j]     = fast_tanh(pa[j]); D[j]     = 1.0f - h[j] * h[j];
                h[4 + j] = fast_tanh(pb[j]); D[4 + j] = 1.0f - h[4 + j] * h[4 + j];
            }
            v8h hh = {(_Float16)h[0], (_Float16)h[1], (_Float16)h[2], (_Float16)h[3],
                      (_Float16)h[4], (_Float16)h[5], (_Float16)h[6], (_Float16)h[7]};
            v8h Dk8 = {(_Float16)D[0], (_Float16)D[1], (_Float16)D[2], (_Float16)D[3],
                       (_Float16)D[4], (_Float16)D[5], (_Float16)D[6], (_Float16)D[7]};
            _Float16* pE = e80 + (ls * 64) * ROWH;
            *(v8h*)pE = hh;
            v4f t1a = icp ? w0a : w1a, t1b = icp ? w0b : w1b;
            v4f t2a = icp ? w1a : w2a, t2b = icp ? w1b : w2b;
            v4f t3a = icp ? w2a : w3a, t3b = icp ? w2b : w3b;
            auto c8 = [](v4f a, v4f bb) {
                v8h rr = {(_Float16)a[0], (_Float16)a[1], (_Float16)a[2], (_Float16)a[3],
                          (_Float16)bb[0], (_Float16)bb[1], (_Float16)bb[2], (_Float16)bb[3]};
                return rr;
            };
            *(v8h*)(pE + 16 * ROWH) = c8(t1a, t1b) * Dk8;
            *(v8h*)(pE + 32 * ROWH) = c8(t2a, t2b) * Dk8;
            *(v8h*)(pE + 48 * ROWH) = c8(t3a, t3b) * Dk8;
        }
        __syncthreads();                               // act0 ready

        hpass(IC<0>{}, rd0, ep1); __syncthreads();     // h1: act0 -> act1
        hpass(IC<1>{}, rd1, ep0); __syncthreads();     // h2: act1 -> act0
        hpass(IC<2>{}, rd0, ep1); __syncthreads();     // h3: act0 -> act1

        // ---- output dot via MFMA: 2 tiles per wave ----
        #pragma unroll
        for (int tt = 0; tt < 2; tt++) {
            int tname = wave * 2 + tt;
            const _Float16* rp = act1 + (tname * 16 + l15) * ROWH + s * 8;
            v4f acc = {0.f, 0.f, 0.f, 0.f};
            acc = __builtin_amdgcn_mfma_f32_16x16x32_f16(wof[0], *(const v8h*)(rp),      acc, 0, 0, 0);
            acc = __builtin_amdgcn_mfma_f32_16x16x32_f16(wof[1], *(const v8h*)(rp + 32), acc, 0, 0, 0);
            acc = __builtin_amdgcn_mfma_f32_16x16x32_f16(wof[2], *(const v8h*)(rp + 64), acc, 0, 0, 0);
            acc = __builtin_amdgcn_mfma_f32_16x16x32_f16(wof[3], *(const v8h*)(rp + 96), acc, 0, 0, 0);
            if (s == 0) cbuf[tname * 16 + l15] = acc[0];
        }
        __syncthreads();                               // cbuf ready

        // ---- quadrature + envelope + chain rule (wave 0, lanes 0-15) ----
        if (wave == 0 && lane < 16) {
            int row = b * 16 + lane;
            if (row < N) {
                const float* rbp = rowb + par * 256 + lane * 16;
                float ah = 0.5f * rbp[0];
                float vic = cbuf[192 + lane];
                float g1  = cbuf[208 + lane];
                float g2  = cbuf[224 + lane];
                float g3  = cbuf[240 + lane];
                float dsum = 0.f, ds1 = 0.f, ds2 = 0.f, ds3 = 0.f;
                const float wq[3] = {0.5555555555555556f, 0.8888888888888889f, 0.5555555555555556f};
                #pragma unroll
                for (int qq = 0; qq < 3; qq++) {
                    float w = wq[qq];
                    dsum += w * cbuf[qq * 64 + lane];
                    ds1  += w * cbuf[qq * 64 + 16 + lane];
                    ds2  += w * cbuf[qq * 64 + 32 + lane];
                    ds3  += w * cbuf[qq * 64 + 48 + lane];
                }
                float tcv  = (vic + bouti) + ah * (dsum + 2.0f * boutd);
                float dtcr = g1 + ah * ds1;
                float dtct = g2 + ah * ds2;
                float dtcp = g3 + ah * ds3;
                float sEnv = rbp[9], dsdr = rbp[10], Aan = rbp[11], dAdr = rbp[12];
                float pot = tcv * sEnv + Aan;
                float gx0 = sEnv * dtcr + tcv * dsdr + dAdr;
                float gx1 = sEnv * dtct;
                float gx2 = sEnv * dtcp;
                float ax = -(gx0 * rbp[1] + gx1 * rbp[4] + gx2 * rbp[7]);
                float ay = -(gx0 * rbp[2] + gx1 * rbp[5] + gx2 * rbp[8]);
                float az = -(gx0 * rbp[3] + gx1 * rbp[6]);
                outPot[row] = pot;
                outAcc[row * 3 + 0] = ax;
                outAcc[row * 3 + 1] = ay;
                outAcc[row * 3 + 2] = az;
            }
        }
    }
}

extern "C" void kernel_launch(void* const* d_in, const int* in_sizes, int n_in,
                              void* d_out, int out_size, void* d_ws, size_t ws_size,
                              hipStream_t stream) {
    (void)n_in; (void)out_size;
    const float* tx     = (const float*)d_in[0];
    const float* dpWin  = (const float*)d_in[1];
    const float* dpBin  = (const float*)d_in[2];
    const float* dpWh   = (const float*)d_in[3];
    const float* dpBh   = (const float*)d_in[4];
    const float* dpWout = (const float*)d_in[5];
    const float* dpBout = (const float*)d_in[6];
    const float* icWin  = (const float*)d_in[7];
    const float* icBin  = (const float*)d_in[8];
    const float* icWh   = (const float*)d_in[9];
    const float* icBh   = (const float*)d_in[10];
    const float* icWout = (const float*)d_in[11];
    const float* icBout = (const float*)d_in[12];

    int N = in_sizes[0] / 4;
    if (ws_size < (size_t)(110592 * sizeof(_Float16))) return;
    _Float16* pack = (_Float16*)d_ws;
    float* outPot = (float*)d_out;
    float* outAcc = outPot + N;

    pack_weights<<<(110592 + 255) / 256, 256, 0, stream>>>(dpWh, icWh, dpWin, icWin,
                                                           dpWout, icWout, pack);

    (void)hipFuncSetAttribute(reinterpret_cast<const void*>(node_main),
                              hipFuncAttributeMaxDynamicSharedMemorySize, SMEM_BYTES);
    node_main<<<256, 512, SMEM_BYTES, stream>>>(tx,
        dpBin, dpBh, icBin, icBh, dpWin, icWin, dpBout, icBout,
        pack, outPot, outAcc, N);
}

// Round 15
// 354.542 us; speedup vs baseline: 1.1701x; 1.1701x over previous
//
#include <hip/hip_runtime.h>

typedef _Float16 v8h __attribute__((ext_vector_type(8)));
typedef _Float16 v4h __attribute__((ext_vector_type(4)));
typedef float    v4f __attribute__((ext_vector_type(4)));

template<int V> struct IC { static constexpr int value = V; };

__device__ __forceinline__ float fast_tanh(float x) {
    float e = __expf(2.0f * x);
    return 1.0f - 2.0f / (e + 1.0f);
}

// ---------------------------------------------------------------------------
// pack layout (halves), unchanged:
//  hidden: idx = ((((pipe*3+l)*8 + nt)*4 + kk)*64 + lane)*8 + j     [0, 98304)
//  L0 (legacy, unused):                                             [98304, 106496)
//  wout A-fragments: 106496 + ((pipe*4 + kk)*64 + lane)*8 + j       [106496, 110592)
// ---------------------------------------------------------------------------
__global__ void pack_weights(const float* __restrict__ dpWh,
                             const float* __restrict__ icWh,
                             const float* __restrict__ dpWin,
                             const float* __restrict__ icWin,
                             const float* __restrict__ dpWout,
                             const float* __restrict__ icWout,
                             _Float16* __restrict__ out) {
    int idx = blockIdx.x * 256 + threadIdx.x;
    if (idx < 98304) {
        int j    = idx & 7;
        int lane = (idx >> 3) & 63;
        int kk   = (idx >> 9) & 3;
        int nt   = (idx >> 11) & 7;
        int lp   = idx >> 14;           // 0..5
        int l    = lp % 3;
        const float* src = (lp >= 3) ? icWh : dpWh;
        int k = kk * 32 + (lane >> 4) * 8 + j;
        int n = nt * 16 + (lane & 15);
        out[idx] = (_Float16)src[(l * 128 + k) * 128 + n];
    } else if (idx < 106496) {
        int f    = idx - 98304;
        int j    = f & 7;
        int lane = (f >> 3) & 63;
        int nt   = (f >> 9) & 7;
        int pipe = (f >> 12) & 1;
        int k = (lane >> 4) * 8 + j;
        int n = nt * 16 + (lane & 15);
        float v = 0.0f;
        if (pipe == 0) { if (k < 4) v = dpWin[k * 128 + n]; }
        else           { if (k < 3) v = icWin[k * 128 + n]; }
        out[idx] = (_Float16)v;
    } else if (idx < 110592) {
        int f    = idx - 106496;
        int j    = f & 7;
        int lane = (f >> 3) & 63;
        int kk   = (f >> 9) & 3;
        int pipe = (f >> 11) & 1;
        float v = 0.0f;
        if ((lane & 15) == 0)
            v = (pipe ? icWout : dpWout)[kk * 32 + (lane >> 4) * 8 + j];
        out[idx] = (_Float16)v;
    }
}

// LDS per block (dynamic, 77824 B -> 2 blocks/CU = 2 independent barrier
// domains; 8 waves/CU total, reg cap 256 so no spill):
//   [0,     34816)  act0 : 128 vrows x ROWH (vrow = setlocal*64 + st*16 + phys)
//   [34816, 69632)  act1
//   [69632, 73728)  btab : f32[8][128]  0=dpBin 1..3=dpBh 4=icBin 5..7=icBh
//   [73728, 77824)  winb : f32[8][128]  0..3=dpWin k, 4..6=icWin k, 7=0
#define ROWH 136
#define SMEM_BYTES 77824
#define PACK_BYTES 221184   // 110592 halves

// Each block processes HALF a 16-row batch: half 0 = quad sets {0,1},
// half 1 = {node2, ic}. Sets are independent until the (linear) combine,
// which runs as a separate tiny kernel reading the partials buffer.
__launch_bounds__(256, 2)
__global__ void node_main(const float* __restrict__ tx,
                          const float* __restrict__ dpBin, const float* __restrict__ dpBh,
                          const float* __restrict__ icBin, const float* __restrict__ icBh,
                          const float* __restrict__ dpWin, const float* __restrict__ icWin,
                          const _Float16* __restrict__ pack,
                          float* __restrict__ part, int N)
{
    extern __shared__ char smem[];
    _Float16* act0 = (_Float16*)smem;
    _Float16* act1 = (_Float16*)(smem + 34816);
    float* btab = (float*)(smem + 69632);
    float* winb = (float*)(smem + 73728);

    const int tid  = threadIdx.x;
    const int wave = tid >> 6;          // 0..3 = 32-feature slice cg
    const int lane = tid & 63;
    const int l15  = lane & 15;
    const int s    = lane >> 4;
    const int cg   = wave;
    const int fb   = cg * 32 + s * 4;   // subslice-0 feature base (C rows)
    const int f8   = cg * 32 + s * 8;   // L0: 8 features per thread

    // ---- stage bias + input-layer weight tables ----
    for (int i = tid; i < 1024; i += 256) {
        int row = i >> 7, col = i & 127;
        float bv, wv;
        if      (row == 0) bv = dpBin[col];
        else if (row <  4) bv = dpBh[(row - 1) * 128 + col];
        else if (row == 4) bv = icBin[col];
        else               bv = icBh[(row - 5) * 128 + col];
        if      (row <  4) wv = dpWin[row * 128 + col];
        else if (row <  7) wv = icWin[(row - 4) * 128 + col];
        else               wv = 0.0f;
        btab[i] = bv;
        winb[i] = wv;
    }

    // ---- persistent dp weights for my 32-feature slice (48 regs) ----
    v8h wreg[3][2][4];
    #pragma unroll
    for (int L = 0; L < 3; L++)
        #pragma unroll
        for (int n2 = 0; n2 < 2; n2++)
            #pragma unroll
            for (int kk = 0; kk < 4; kk++)
                wreg[L][n2][kk] = *(const v8h*)(pack + (((L * 8 + cg * 2 + n2) * 4 + kk) << 9) + (lane << 3));
    __syncthreads();

    // ---- static LDS bases ----
    _Float16* ep0 = act0 + l15 * ROWH + fb;
    _Float16* ep1 = act1 + l15 * ROWH + fb;
    const _Float16* rd0 = act0 + l15 * ROWH + s * 8;
    const _Float16* rd1 = act1 + l15 * ROWH + s * 8;
    _Float16* e80 = act0 + l15 * ROWH + f8;

    auto epi_p = [&](v4f acc, v4h& Dkh, _Float16* p) {
        float h0 = fast_tanh(acc[0]), h1 = fast_tanh(acc[1]);
        float h2 = fast_tanh(acc[2]), h3 = fast_tanh(acc[3]);
        Dkh[0] = (_Float16)(1.0f - h0 * h0);
        Dkh[1] = (_Float16)(1.0f - h1 * h1);
        Dkh[2] = (_Float16)(1.0f - h2 * h2);
        Dkh[3] = (_Float16)(1.0f - h3 * h3);
        v4h w = {(_Float16)h0, (_Float16)h1, (_Float16)h2, (_Float16)h3};
        *(v4h*)p = w;
    };
    auto epi_t = [&](v4f acc, const v4h& Dkh, _Float16* p) {
        v4h av = {(_Float16)acc[0], (_Float16)acc[1],
                  (_Float16)acc[2], (_Float16)acc[3]};
        *(v4h*)p = av * Dkh;                            // pk_mul
    };

    // 4 tiles of one 64-vrow set (B-frags read once, feed both subslices)
    auto quad = [&](const v8h (&W)[2][4], const float* br,
                    const _Float16* rb, _Float16* wb, int jbase) {
        v4h Dk0, Dk1;
        #pragma unroll
        for (int q = 0; q < 4; q++) {
            const int ro = (jbase + q) * (16 * ROWH);
            v8h b0 = *(const v8h*)(rb + ro);
            v8h b1 = *(const v8h*)(rb + ro + 32);
            v8h b2 = *(const v8h*)(rb + ro + 64);
            v8h b3 = *(const v8h*)(rb + ro + 96);
            v4f a0, a1;
            if (q == 0) { a0 = *(const v4f*)br; a1 = *(const v4f*)(br + 16); }
            else { v4f z = {0.f, 0.f, 0.f, 0.f}; a0 = z; a1 = z; }
            a0 = __builtin_amdgcn_mfma_f32_16x16x32_f16(W[0][0], b0, a0, 0, 0, 0);
            a1 = __builtin_amdgcn_mfma_f32_16x16x32_f16(W[1][0], b0, a1, 0, 0, 0);
            a0 = __builtin_amdgcn_mfma_f32_16x16x32_f16(W[0][1], b1, a0, 0, 0, 0);
            a1 = __builtin_amdgcn_mfma_f32_16x16x32_f16(W[1][1], b1, a1, 0, 0, 0);
            a0 = __builtin_amdgcn_mfma_f32_16x16x32_f16(W[0][2], b2, a0, 0, 0, 0);
            a1 = __builtin_amdgcn_mfma_f32_16x16x32_f16(W[1][2], b2, a1, 0, 0, 0);
            a0 = __builtin_amdgcn_mfma_f32_16x16x32_f16(W[0][3], b3, a0, 0, 0, 0);
            a1 = __builtin_amdgcn_mfma_f32_16x16x32_f16(W[1][3], b3, a1, 0, 0, 0);
            _Float16* p = wb + (jbase + q) * (16 * ROWH);
            if (q == 0) { epi_p(a0, Dk0, p); epi_p(a1, Dk1, p + 16); }
            else        { epi_t(a0, Dk0, p); epi_t(a1, Dk1, p + 16); }
        }
    };

    // one hidden layer over this block's 2 sets (8 tiles). half==1: local
    // set 1 is the ic pipe, weights streamed transiently (L2-resident).
    auto hpass = [&](auto Lc, const _Float16* rb, _Float16* wb, int half) {
        constexpr int L = decltype(Lc)::value;
        quad(wreg[L], btab + (1 + L) * 128 + fb, rb, wb, 0);      // set A (dp)
        if (half) {
            v8h icw[2][4];
            #pragma unroll
            for (int n2 = 0; n2 < 2; n2++)
                #pragma unroll
                for (int kk = 0; kk < 4; kk++)
                    icw[n2][kk] = *(const v8h*)(pack + ((((3 + L) * 8 + cg * 2 + n2) * 4 + kk) << 9) + (lane << 3));
            quad(icw, btab + (5 + L) * 128 + fb, rb, wb, 4);      // set B (ic)
        } else {
            quad(wreg[L], btab + (1 + L) * 128 + fb, rb, wb, 4);  // set B (dp)
        }
    };

    const float NP0 = 1.0f - 0.7745966692414834f;   // GL node+1
    const float NP2 = 1.0f + 0.7745966692414834f;

    const int nun = (((N + 15) >> 4) << 1);
    for (int u = blockIdx.x; u < nun; u += gridDim.x) {
        const int b    = u >> 1;
        const int half = u & 1;

        // ---- geometry (per-lane, inputs only — derivatives live in combine) ----
        int prow = b * 16 + l15;
        float4 qq = (prow < N) ? ((const float4*)tx)[prow] : make_float4(0.f, 1.f, 1.f, 1.f);
        float t = qq.x, x = qq.y, y = qq.z, z = qq.w;
        float r  = sqrtf(x * x + y * y + z * z + 1e-12f);
        float rinv = 1.0f / r;
        float uc = fminf(1.0f, fmaxf(-1.0f, z * rinv));
        float th = acosf(uc);
        float ph = atan2f(y, x);

        // ---- L0 (fp32 VALU): 2 local sets x 8 features/thread -> act0 ----
        #pragma unroll
        for (int ls = 0; ls < 2; ls++) {
            const bool icp = (half == 1) && (ls == 1);
            const float* wb = winb + (icp ? 512 : 0);
            v4f pa = *(const v4f*)(btab + (icp ? 512 : 0) + f8);
            v4f pb = *(const v4f*)(btab + (icp ? 512 : 0) + f8 + 4);
            v4f w0a = *(const v4f*)(wb + f8),       w0b = *(const v4f*)(wb + f8 + 4);
            v4f w1a = *(const v4f*)(wb + 128 + f8), w1b = *(const v4f*)(wb + 128 + f8 + 4);
            v4f w2a = *(const v4f*)(wb + 256 + f8), w2b = *(const v4f*)(wb + 256 + f8 + 4);
            v4f w3a, w3b;
            if (icp) { v4f zz = {0.f, 0.f, 0.f, 0.f}; w3a = zz; w3b = zz; }
            else { w3a = *(const v4f*)(wb + 384 + f8); w3b = *(const v4f*)(wb + 384 + f8 + 4); }
            float i0, i1, i2, i3;
            if (icp) { i0 = r; i1 = th; i2 = ph; i3 = 0.0f; }
            else {
                float np1 = half ? NP2 : (ls ? 1.0f : NP0);
                i0 = 0.5f * t * np1; i1 = r; i2 = th; i3 = ph;
            }
            #pragma unroll
            for (int j = 0; j < 4; j++) {
                pa[j] += i0 * w0a[j] + i1 * w1a[j] + i2 * w2a[j] + i3 * w3a[j];
                pb[j] += i0 * w0b[j] + i1 * w1b[j] + i2 * w2b[j] + i3 * w3b[j];
            }
            float h[8], D[8];
            #pragma unroll
            for (int j = 0; j < 4; j++) {
                h[j]     = fast_tanh(pa[j]); D[j]     = 1.0f - h[j] * h[j];
                h[4 + j] = fast_tanh(pb[j]); D[4 + j] = 1.0f - h[4 + j] * h[4 + j];
            }
            v8h hh = {(_Float16)h[0], (_Float16)h[1], (_Float16)h[2], (_Float16)h[3],
                      (_Float16)h[4], (_Float16)h[5], (_Float16)h[6], (_Float16)h[7]};
            v8h Dk8 = {(_Float16)D[0], (_Float16)D[1], (_Float16)D[2], (_Float16)D[3],
                       (_Float16)D[4], (_Float16)D[5], (_Float16)D[6], (_Float16)D[7]};
            _Float16* pE = e80 + (ls * 64) * ROWH;
            *(v8h*)pE = hh;
            v4f t1a = icp ? w0a : w1a, t1b = icp ? w0b : w1b;
            v4f t2a = icp ? w1a : w2a, t2b = icp ? w1b : w2b;
            v4f t3a = icp ? w2a : w3a, t3b = icp ? w2b : w3b;
            auto c8 = [](v4f a, v4f bb) {
                v8h rr = {(_Float16)a[0], (_Float16)a[1], (_Float16)a[2], (_Float16)a[3],
                          (_Float16)bb[0], (_Float16)bb[1], (_Float16)bb[2], (_Float16)bb[3]};
                return rr;
            };
            *(v8h*)(pE + 16 * ROWH) = c8(t1a, t1b) * Dk8;
            *(v8h*)(pE + 32 * ROWH) = c8(t2a, t2b) * Dk8;
            *(v8h*)(pE + 48 * ROWH) = c8(t3a, t3b) * Dk8;
        }
        __syncthreads();                               // act0 ready

        hpass(IC<0>{}, rd0, ep1, half); __syncthreads();   // h1: act0 -> act1
        hpass(IC<1>{}, rd1, ep0, half); __syncthreads();   // h2: act1 -> act0
        hpass(IC<2>{}, rd0, ep1, half); __syncthreads();   // h3: act0 -> act1

        // ---- out-dot via MFMA; write tile results straight to partials ----
        {
            const bool icout = (half == 1) && (wave >= 2);
            const _Float16* wsf = pack + 106496 + (icout ? 2048 : 0) + (lane << 3);
            v8h wof0 = *(const v8h*)(wsf);
            v8h wof1 = *(const v8h*)(wsf + 512);
            v8h wof2 = *(const v8h*)(wsf + 1024);
            v8h wof3 = *(const v8h*)(wsf + 1536);
            #pragma unroll
            for (int tt = 0; tt < 2; tt++) {
                int t8 = wave * 2 + tt;
                const _Float16* rp = act1 + (t8 * 16 + l15) * ROWH + s * 8;
                v4f acc = {0.f, 0.f, 0.f, 0.f};
                acc = __builtin_amdgcn_mfma_f32_16x16x32_f16(wof0, *(const v8h*)(rp),      acc, 0, 0, 0);
                acc = __builtin_amdgcn_mfma_f32_16x16x32_f16(wof1, *(const v8h*)(rp + 32), acc, 0, 0, 0);
                acc = __builtin_amdgcn_mfma_f32_16x16x32_f16(wof2, *(const v8h*)(rp + 64), acc, 0, 0, 0);
                acc = __builtin_amdgcn_mfma_f32_16x16x32_f16(wof3, *(const v8h*)(rp + 96), acc, 0, 0, 0);
                if (s == 0) part[b * 256 + half * 128 + t8 * 16 + l15] = acc[0];
            }
        }
        // no barrier: next L0 writes act0 (dead after h3 barrier); act1 reads
        // complete before any wave passes the next act0 barrier.
    }
}

// Tiny memory-bound combine: quadrature + envelope + chain rule (all linear
// in the per-set network outputs stored in `part`).
__global__ void node_combine(const float* __restrict__ tx, const float* __restrict__ part,
                             const float* __restrict__ dpBout, const float* __restrict__ icBout,
                             float* __restrict__ outPot, float* __restrict__ outAcc, int N)
{
    int row = blockIdx.x * 256 + threadIdx.x;
    if (row >= N) return;
    float4 q = ((const float4*)tx)[row];
    float t = q.x, x = q.y, y = q.z, z = q.w;
    float r  = sqrtf(x * x + y * y + z * z + 1e-12f);
    float rinv = 1.0f / r;
    float uc = fminf(1.0f, fmaxf(-1.0f, z * rinv));
    float rinv3 = rinv * rinv * rinv;
    float dacos = -1.0f / sqrtf(fmaxf(1.0f - uc * uc, 1e-30f));
    float dthx = dacos * (-x * z * rinv3);
    float dthy = dacos * (-y * z * rinv3);
    float dthz = dacos * (rinv - z * z * rinv3);
    float rho2 = fmaxf(x * x + y * y, 1e-30f);
    float dphx = -y / rho2;
    float dphy =  x / rho2;
    float opr  = 1.0f + r;
    float sEnv = -1.0f / opr;
    float dsdr =  1.0f / (opr * opr);
    float den  = r * r + 0.1f;
    float isq  = 1.0f / sqrtf(den);
    float Aan  = -isq;
    float dAdr = r * isq * isq * isq;

    const float* pr = part + ((row >> 4) << 8) + (row & 15);
    const float wq0 = 0.5555555555555556f, wq1 = 0.8888888888888889f, wq2 = 0.5555555555555556f;
    float dsum = wq0 * pr[0]  + wq1 * pr[64]  + wq2 * pr[128];
    float ds1  = wq0 * pr[16] + wq1 * pr[80]  + wq2 * pr[144];
    float ds2  = wq0 * pr[32] + wq1 * pr[96]  + wq2 * pr[160];
    float ds3  = wq0 * pr[48] + wq1 * pr[112] + wq2 * pr[176];
    float vic = pr[192], g1 = pr[208], g2 = pr[224], g3 = pr[240];

    float ah = 0.5f * t;
    float tcv  = (vic + icBout[0]) + ah * (dsum + 2.0f * dpBout[0]);
    float dtcr = g1 + ah * ds1;
    float dtct = g2 + ah * ds2;
    float dtcp = g3 + ah * ds3;
    float pot = tcv * sEnv + Aan;
    float gx0 = sEnv * dtcr + tcv * dsdr + dAdr;
    float gx1 = sEnv * dtct;
    float gx2 = sEnv * dtcp;
    float ax = -(gx0 * (x * rinv) + gx1 * dthx + gx2 * dphx);
    float ay = -(gx0 * (y * rinv) + gx1 * dthy + gx2 * dphy);
    float az = -(gx0 * (z * rinv) + gx1 * dthz);
    outPot[row] = pot;
    outAcc[row * 3 + 0] = ax;
    outAcc[row * 3 + 1] = ay;
    outAcc[row * 3 + 2] = az;
}

extern "C" void kernel_launch(void* const* d_in, const int* in_sizes, int n_in,
                              void* d_out, int out_size, void* d_ws, size_t ws_size,
                              hipStream_t stream) {
    (void)n_in; (void)out_size;
    const float* tx     = (const float*)d_in[0];
    const float* dpWin  = (const float*)d_in[1];
    const float* dpBin  = (const float*)d_in[2];
    const float* dpWh   = (const float*)d_in[3];
    const float* dpBh   = (const float*)d_in[4];
    const float* dpWout = (const float*)d_in[5];
    const float* dpBout = (const float*)d_in[6];
    const float* icWin  = (const float*)d_in[7];
    const float* icBin  = (const float*)d_in[8];
    const float* icWh   = (const float*)d_in[9];
    const float* icBh   = (const float*)d_in[10];
    const float* icWout = (const float*)d_in[11];
    const float* icBout = (const float*)d_in[12];

    int N = in_sizes[0] / 4;
    int nbat = (N + 15) >> 4;
    size_t need = (size_t)PACK_BYTES + (size_t)nbat * 256 * sizeof(float);
    if (ws_size < need) return;
    _Float16* pack = (_Float16*)d_ws;
    float* part = (float*)((char*)d_ws + PACK_BYTES);
    float* outPot = (float*)d_out;
    float* outAcc = outPot + N;

    pack_weights<<<(110592 + 255) / 256, 256, 0, stream>>>(dpWh, icWh, dpWin, icWin,
                                                           dpWout, icWout, pack);

    (void)hipFuncSetAttribute(reinterpret_cast<const void*>(node_main),
                              hipFuncAttributeMaxDynamicSharedMemorySize, SMEM_BYTES);
    node_main<<<512, 256, SMEM_BYTES, stream>>>(tx,
        dpBin, dpBh, icBin, icBh, dpWin, icWin,
        pack, part, N);

    node_combine<<<(N + 255) / 256, 256, 0, stream>>>(tx, part, dpBout, icBout,
                                                      outPot, outAcc, N);
}

// Round 16
// 283.697 us; speedup vs baseline: 1.4623x; 1.2497x over previous
//
#include <hip/hip_runtime.h>

typedef _Float16 v8h __attribute__((ext_vector_type(8)));
typedef _Float16 v4h __attribute__((ext_vector_type(4)));
typedef float    v4f __attribute__((ext_vector_type(4)));

template<int V> struct IC { static constexpr int value = V; };

// rcp-based tanh: IEEE div would expand to ~10 instr; v_rcp_f32 is 1.
__device__ __forceinline__ float fast_tanh(float x) {
    float e = __expf(2.0f * x);
    return 1.0f - 2.0f * __builtin_amdgcn_rcpf(e + 1.0f);
}

// ---------------------------------------------------------------------------
// pack layout (halves), unchanged:
//  hidden: idx = ((((pipe*3+l)*8 + nt)*4 + kk)*64 + lane)*8 + j     [0, 98304)
//  L0 (legacy, unused):                                             [98304, 106496)
//  wout A-fragments: 106496 + ((pipe*4 + kk)*64 + lane)*8 + j       [106496, 110592)
// ---------------------------------------------------------------------------
__global__ void pack_weights(const float* __restrict__ dpWh,
                             const float* __restrict__ icWh,
                             const float* __restrict__ dpWin,
                             const float* __restrict__ icWin,
                             const float* __restrict__ dpWout,
                             const float* __restrict__ icWout,
                             _Float16* __restrict__ out) {
    int idx = blockIdx.x * 256 + threadIdx.x;
    if (idx < 98304) {
        int j    = idx & 7;
        int lane = (idx >> 3) & 63;
        int kk   = (idx >> 9) & 3;
        int nt   = (idx >> 11) & 7;
        int lp   = idx >> 14;           // 0..5
        int l    = lp % 3;
        const float* src = (lp >= 3) ? icWh : dpWh;
        int k = kk * 32 + (lane >> 4) * 8 + j;
        int n = nt * 16 + (lane & 15);
        out[idx] = (_Float16)src[(l * 128 + k) * 128 + n];
    } else if (idx < 106496) {
        int f    = idx - 98304;
        int j    = f & 7;
        int lane = (f >> 3) & 63;
        int nt   = (f >> 9) & 7;
        int pipe = (f >> 12) & 1;
        int k = (lane >> 4) * 8 + j;
        int n = nt * 16 + (lane & 15);
        float v = 0.0f;
        if (pipe == 0) { if (k < 4) v = dpWin[k * 128 + n]; }
        else           { if (k < 3) v = icWin[k * 128 + n]; }
        out[idx] = (_Float16)v;
    } else if (idx < 110592) {
        int f    = idx - 106496;
        int j    = f & 7;
        int lane = (f >> 3) & 63;
        int kk   = (f >> 9) & 3;
        int pipe = (f >> 11) & 1;
        float v = 0.0f;
        if ((lane & 15) == 0)
            v = (pipe ? icWout : dpWout)[kk * 32 + (lane >> 4) * 8 + j];
        out[idx] = (_Float16)v;
    }
}

// Precompute modified spherical coords per row: sph[row] = (t, r, th, ph).
// Removes acos/atan2/sqrt/IEEE-div from every unit of the main kernel.
__global__ void sph_prep(const float* __restrict__ tx, float* __restrict__ sph, int N) {
    int row = blockIdx.x * 256 + threadIdx.x;
    if (row >= N) return;
    float4 q = ((const float4*)tx)[row];
    float x = q.y, y = q.z, z = q.w;
    float r  = sqrtf(x * x + y * y + z * z + 1e-12f);
    float uc = fminf(1.0f, fmaxf(-1.0f, z / r));
    ((float4*)sph)[row] = make_float4(q.x, r, acosf(uc), atan2f(y, x));
}

// LDS per block (dynamic, 77824 B -> 2 blocks/CU = 2 independent barrier
// domains; 8 waves/CU total, reg cap 256 so no spill):
//   [0,     34816)  act0 : 128 vrows x ROWH (vrow = setlocal*64 + st*16 + phys)
//   [34816, 69632)  act1
//   [69632, 73728)  btab : f32[8][128]  0=dpBin 1..3=dpBh 4=icBin 5..7=icBh
//   [73728, 77824)  winb : f32[8][128]  0..3=dpWin k, 4..6=icWin k, 7=0
#define ROWH 136
#define SMEM_BYTES 77824
#define PACK_BYTES 221184   // 110592 halves

__launch_bounds__(256, 2)
__global__ void node_main(const float* __restrict__ sph,
                          const float* __restrict__ dpBin, const float* __restrict__ dpBh,
                          const float* __restrict__ icBin, const float* __restrict__ icBh,
                          const float* __restrict__ dpWin, const float* __restrict__ icWin,
                          const _Float16* __restrict__ pack,
                          float* __restrict__ part, int N)
{
    extern __shared__ char smem[];
    _Float16* act0 = (_Float16*)smem;
    _Float16* act1 = (_Float16*)(smem + 34816);
    float* btab = (float*)(smem + 69632);
    float* winb = (float*)(smem + 73728);

    const int tid  = threadIdx.x;
    const int wave = tid >> 6;          // 0..3 = 32-feature slice cg
    const int lane = tid & 63;
    const int l15  = lane & 15;
    const int s    = lane >> 4;
    const int cg   = wave;
    const int fb   = cg * 32 + s * 4;   // subslice-0 feature base (C rows)
    const int f8   = cg * 32 + s * 8;   // L0: 8 features per thread

    // ---- stage bias + input-layer weight tables ----
    for (int i = tid; i < 1024; i += 256) {
        int row = i >> 7, col = i & 127;
        float bv, wv;
        if      (row == 0) bv = dpBin[col];
        else if (row <  4) bv = dpBh[(row - 1) * 128 + col];
        else if (row == 4) bv = icBin[col];
        else               bv = icBh[(row - 5) * 128 + col];
        if      (row <  4) wv = dpWin[row * 128 + col];
        else if (row <  7) wv = icWin[(row - 4) * 128 + col];
        else               wv = 0.0f;
        btab[i] = bv;
        winb[i] = wv;
    }

    // ---- persistent dp weights for my 32-feature slice (48 regs) ----
    v8h wreg[3][2][4];
    #pragma unroll
    for (int L = 0; L < 3; L++)
        #pragma unroll
        for (int n2 = 0; n2 < 2; n2++)
            #pragma unroll
            for (int kk = 0; kk < 4; kk++)
                wreg[L][n2][kk] = *(const v8h*)(pack + (((L * 8 + cg * 2 + n2) * 4 + kk) << 9) + (lane << 3));
    __syncthreads();

    // ---- static LDS bases ----
    _Float16* ep0 = act0 + l15 * ROWH + fb;
    _Float16* ep1 = act1 + l15 * ROWH + fb;
    const _Float16* rd0 = act0 + l15 * ROWH + s * 8;
    const _Float16* rd1 = act1 + l15 * ROWH + s * 8;
    _Float16* e80 = act0 + l15 * ROWH + f8;

    auto epi_p = [&](v4f acc, v4h& Dkh, _Float16* p) {
        float h0 = fast_tanh(acc[0]), h1 = fast_tanh(acc[1]);
        float h2 = fast_tanh(acc[2]), h3 = fast_tanh(acc[3]);
        Dkh[0] = (_Float16)(1.0f - h0 * h0);
        Dkh[1] = (_Float16)(1.0f - h1 * h1);
        Dkh[2] = (_Float16)(1.0f - h2 * h2);
        Dkh[3] = (_Float16)(1.0f - h3 * h3);
        v4h w = {(_Float16)h0, (_Float16)h1, (_Float16)h2, (_Float16)h3};
        *(v4h*)p = w;
    };
    auto epi_t = [&](v4f acc, const v4h& Dkh, _Float16* p) {
        v4h av = {(_Float16)acc[0], (_Float16)acc[1],
                  (_Float16)acc[2], (_Float16)acc[3]};
        *(v4h*)p = av * Dkh;                            // pk_mul
    };

    // 4 tiles of one 64-vrow set (B-frags read once, feed both subslices)
    auto quad = [&](const v8h (&W)[2][4], const float* br,
                    const _Float16* rb, _Float16* wb, int jbase) {
        v4h Dk0, Dk1;
        #pragma unroll
        for (int q = 0; q < 4; q++) {
            const int ro = (jbase + q) * (16 * ROWH);
            v8h b0 = *(const v8h*)(rb + ro);
            v8h b1 = *(const v8h*)(rb + ro + 32);
            v8h b2 = *(const v8h*)(rb + ro + 64);
            v8h b3 = *(const v8h*)(rb + ro + 96);
            v4f a0, a1;
            if (q == 0) { a0 = *(const v4f*)br; a1 = *(const v4f*)(br + 16); }
            else { v4f z = {0.f, 0.f, 0.f, 0.f}; a0 = z; a1 = z; }
            a0 = __builtin_amdgcn_mfma_f32_16x16x32_f16(W[0][0], b0, a0, 0, 0, 0);
            a1 = __builtin_amdgcn_mfma_f32_16x16x32_f16(W[1][0], b0, a1, 0, 0, 0);
            a0 = __builtin_amdgcn_mfma_f32_16x16x32_f16(W[0][1], b1, a0, 0, 0, 0);
            a1 = __builtin_amdgcn_mfma_f32_16x16x32_f16(W[1][1], b1, a1, 0, 0, 0);
            a0 = __builtin_amdgcn_mfma_f32_16x16x32_f16(W[0][2], b2, a0, 0, 0, 0);
            a1 = __builtin_amdgcn_mfma_f32_16x16x32_f16(W[1][2], b2, a1, 0, 0, 0);
            a0 = __builtin_amdgcn_mfma_f32_16x16x32_f16(W[0][3], b3, a0, 0, 0, 0);
            a1 = __builtin_amdgcn_mfma_f32_16x16x32_f16(W[1][3], b3, a1, 0, 0, 0);
            _Float16* p = wb + (jbase + q) * (16 * ROWH);
            if (q == 0) { epi_p(a0, Dk0, p); epi_p(a1, Dk1, p + 16); }
            else        { epi_t(a0, Dk0, p); epi_t(a1, Dk1, p + 16); }
        }
    };

    // one hidden layer over this block's 2 sets (8 tiles). half==1: local
    // set 1 is the ic pipe, weights streamed transiently (L2-resident).
    auto hpass = [&](auto Lc, const _Float16* rb, _Float16* wb, int half) {
        constexpr int L = decltype(Lc)::value;
        quad(wreg[L], btab + (1 + L) * 128 + fb, rb, wb, 0);      // set A (dp)
        if (half) {
            v8h icw[2][4];
            #pragma unroll
            for (int n2 = 0; n2 < 2; n2++)
                #pragma unroll
                for (int kk = 0; kk < 4; kk++)
                    icw[n2][kk] = *(const v8h*)(pack + ((((3 + L) * 8 + cg * 2 + n2) * 4 + kk) << 9) + (lane << 3));
            quad(icw, btab + (5 + L) * 128 + fb, rb, wb, 4);      // set B (ic)
        } else {
            quad(wreg[L], btab + (1 + L) * 128 + fb, rb, wb, 4);  // set B (dp)
        }
    };

    const float NP0 = 1.0f - 0.7745966692414834f;   // GL node+1
    const float NP2 = 1.0f + 0.7745966692414834f;

    const int nun = (((N + 15) >> 4) << 1);
    for (int u = blockIdx.x; u < nun; u += gridDim.x) {
        const int b    = u >> 1;
        const int half = u & 1;

        // ---- geometry: precomputed (t, r, th, ph) ----
        int prow = b * 16 + l15;
        float4 sp = (prow < N) ? ((const float4*)sph)[prow]
                               : make_float4(0.f, 1.f, 1.f, 1.f);
        float t = sp.x, r = sp.y, th = sp.z, ph = sp.w;

        // ---- L0 (fp32 VALU): 2 local sets x 8 features/thread -> act0 ----
        #pragma unroll
        for (int ls = 0; ls < 2; ls++) {
            const bool icp = (half == 1) && (ls == 1);
            const float* wb = winb + (icp ? 512 : 0);
            v4f pa = *(const v4f*)(btab + (icp ? 512 : 0) + f8);
            v4f pb = *(const v4f*)(btab + (icp ? 512 : 0) + f8 + 4);
            v4f w0a = *(const v4f*)(wb + f8),       w0b = *(const v4f*)(wb + f8 + 4);
            v4f w1a = *(const v4f*)(wb + 128 + f8), w1b = *(const v4f*)(wb + 128 + f8 + 4);
            v4f w2a = *(const v4f*)(wb + 256 + f8), w2b = *(const v4f*)(wb + 256 + f8 + 4);
            v4f w3a, w3b;
            if (icp) { v4f zz = {0.f, 0.f, 0.f, 0.f}; w3a = zz; w3b = zz; }
            else { w3a = *(const v4f*)(wb + 384 + f8); w3b = *(const v4f*)(wb + 384 + f8 + 4); }
            float i0, i1, i2, i3;
            if (icp) { i0 = r; i1 = th; i2 = ph; i3 = 0.0f; }
            else {
                float np1 = half ? NP2 : (ls ? 1.0f : NP0);
                i0 = 0.5f * t * np1; i1 = r; i2 = th; i3 = ph;
            }
            #pragma unroll
            for (int j = 0; j < 4; j++) {
                pa[j] += i0 * w0a[j] + i1 * w1a[j] + i2 * w2a[j] + i3 * w3a[j];
                pb[j] += i0 * w0b[j] + i1 * w1b[j] + i2 * w2b[j] + i3 * w3b[j];
            }
            float h[8], D[8];
            #pragma unroll
            for (int j = 0; j < 4; j++) {
                h[j]     = fast_tanh(pa[j]); D[j]     = 1.0f - h[j] * h[j];
                h[4 + j] = fast_tanh(pb[j]); D[4 + j] = 1.0f - h[4 + j] * h[4 + j];
            }
            v8h hh = {(_Float16)h[0], (_Float16)h[1], (_Float16)h[2], (_Float16)h[3],
                      (_Float16)h[4], (_Float16)h[5], (_Float16)h[6], (_Float16)h[7]};
            v8h Dk8 = {(_Float16)D[0], (_Float16)D[1], (_Float16)D[2], (_Float16)D[3],
                       (_Float16)D[4], (_Float16)D[5], (_Float16)D[6], (_Float16)D[7]};
            _Float16* pE = e80 + (ls * 64) * ROWH;
            *(v8h*)pE = hh;
            v4f t1a = icp ? w0a : w1a, t1b = icp ? w0b : w1b;
            v4f t2a = icp ? w1a : w2a, t2b = icp ? w1b : w2b;
            v4f t3a = icp ? w2a : w3a, t3b = icp ? w2b : w3b;
            auto c8 = [](v4f a, v4f bb) {
                v8h rr = {(_Float16)a[0], (_Float16)a[1], (_Float16)a[2], (_Float16)a[3],
                          (_Float16)bb[0], (_Float16)bb[1], (_Float16)bb[2], (_Float16)bb[3]};
                return rr;
            };
            *(v8h*)(pE + 16 * ROWH) = c8(t1a, t1b) * Dk8;
            *(v8h*)(pE + 32 * ROWH) = c8(t2a, t2b) * Dk8;
            *(v8h*)(pE + 48 * ROWH) = c8(t3a, t3b) * Dk8;
        }
        __syncthreads();                               // act0 ready

        hpass(IC<0>{}, rd0, ep1, half); __syncthreads();   // h1: act0 -> act1
        hpass(IC<1>{}, rd1, ep0, half); __syncthreads();   // h2: act1 -> act0
        hpass(IC<2>{}, rd0, ep1, half); __syncthreads();   // h3: act0 -> act1

        // ---- out-dot via MFMA; write tile results straight to partials ----
        {
            const bool icout = (half == 1) && (wave >= 2);
            const _Float16* wsf = pack + 106496 + (icout ? 2048 : 0) + (lane << 3);
            v8h wof0 = *(const v8h*)(wsf);
            v8h wof1 = *(const v8h*)(wsf + 512);
            v8h wof2 = *(const v8h*)(wsf + 1024);
            v8h wof3 = *(const v8h*)(wsf + 1536);
            #pragma unroll
            for (int tt = 0; tt < 2; tt++) {
                int t8 = wave * 2 + tt;
                const _Float16* rp = act1 + (t8 * 16 + l15) * ROWH + s * 8;
                v4f acc = {0.f, 0.f, 0.f, 0.f};
                acc = __builtin_amdgcn_mfma_f32_16x16x32_f16(wof0, *(const v8h*)(rp),      acc, 0, 0, 0);
                acc = __builtin_amdgcn_mfma_f32_16x16x32_f16(wof1, *(const v8h*)(rp + 32), acc, 0, 0, 0);
                acc = __builtin_amdgcn_mfma_f32_16x16x32_f16(wof2, *(const v8h*)(rp + 64), acc, 0, 0, 0);
                acc = __builtin_amdgcn_mfma_f32_16x16x32_f16(wof3, *(const v8h*)(rp + 96), acc, 0, 0, 0);
                if (s == 0) part[b * 256 + half * 128 + t8 * 16 + l15] = acc[0];
            }
        }
        // no barrier: next L0 writes act0 (dead after h3 barrier); act1 reads
        // complete before any wave passes the next act0 barrier.
    }
}

// Tiny memory-bound combine: quadrature + envelope + chain rule (linear in
// the per-set network outputs stored in `part`). Exact f32 math as r15.
__global__ void node_combine(const float* __restrict__ tx, const float* __restrict__ part,
                             const float* __restrict__ dpBout, const float* __restrict__ icBout,
                             float* __restrict__ outPot, float* __restrict__ outAcc, int N)
{
    int row = blockIdx.x * 256 + threadIdx.x;
    if (row >= N) return;
    float4 q = ((const float4*)tx)[row];
    float t = q.x, x = q.y, y = q.z, z = q.w;
    float r  = sqrtf(x * x + y * y + z * z + 1e-12f);
    float rinv = 1.0f / r;
    float uc = fminf(1.0f, fmaxf(-1.0f, z * rinv));
    float rinv3 = rinv * rinv * rinv;
    float dacos = -1.0f / sqrtf(fmaxf(1.0f - uc * uc, 1e-30f));
    float dthx = dacos * (-x * z * rinv3);
    float dthy = dacos * (-y * z * rinv3);
    float dthz = dacos * (rinv - z * z * rinv3);
    float rho2 = fmaxf(x * x + y * y, 1e-30f);
    float dphx = -y / rho2;
    float dphy =  x / rho2;
    float opr  = 1.0f + r;
    float sEnv = -1.0f / opr;
    float dsdr =  1.0f / (opr * opr);
    float den  = r * r + 0.1f;
    float isq  = 1.0f / sqrtf(den);
    float Aan  = -isq;
    float dAdr = r * isq * isq * isq;

    const float* pr = part + ((row >> 4) << 8) + (row & 15);
    const float wq0 = 0.5555555555555556f, wq1 = 0.8888888888888889f, wq2 = 0.5555555555555556f;
    float dsum = wq0 * pr[0]  + wq1 * pr[64]  + wq2 * pr[128];
    float ds1  = wq0 * pr[16] + wq1 * pr[80]  + wq2 * pr[144];
    float ds2  = wq0 * pr[32] + wq1 * pr[96]  + wq2 * pr[160];
    float ds3  = wq0 * pr[48] + wq1 * pr[112] + wq2 * pr[176];
    float vic = pr[192], g1 = pr[208], g2 = pr[224], g3 = pr[240];

    float ah = 0.5f * t;
    float tcv  = (vic + icBout[0]) + ah * (dsum + 2.0f * dpBout[0]);
    float dtcr = g1 + ah * ds1;
    float dtct = g2 + ah * ds2;
    float dtcp = g3 + ah * ds3;
    float pot = tcv * sEnv + Aan;
    float gx0 = sEnv * dtcr + tcv * dsdr + dAdr;
    float gx1 = sEnv * dtct;
    float gx2 = sEnv * dtcp;
    float ax = -(gx0 * (x * rinv) + gx1 * dthx + gx2 * dphx);
    float ay = -(gx0 * (y * rinv) + gx1 * dthy + gx2 * dphy);
    float az = -(gx0 * (z * rinv) + gx1 * dthz);
    outPot[row] = pot;
    outAcc[row * 3 + 0] = ax;
    outAcc[row * 3 + 1] = ay;
    outAcc[row * 3 + 2] = az;
}

extern "C" void kernel_launch(void* const* d_in, const int* in_sizes, int n_in,
                              void* d_out, int out_size, void* d_ws, size_t ws_size,
                              hipStream_t stream) {
    (void)n_in; (void)out_size;
    const float* tx     = (const float*)d_in[0];
    const float* dpWin  = (const float*)d_in[1];
    const float* dpBin  = (const float*)d_in[2];
    const float* dpWh   = (const float*)d_in[3];
    const float* dpBh   = (const float*)d_in[4];
    const float* dpWout = (const float*)d_in[5];
    const float* dpBout = (const float*)d_in[6];
    const float* icWin  = (const float*)d_in[7];
    const float* icBin  = (const float*)d_in[8];
    const float* icWh   = (const float*)d_in[9];
    const float* icBh   = (const float*)d_in[10];
    const float* icWout = (const float*)d_in[11];
    const float* icBout = (const float*)d_in[12];

    int N = in_sizes[0] / 4;
    int nbat = (N + 15) >> 4;
    size_t part_bytes = (size_t)nbat * 256 * sizeof(float);
    size_t sph_off = (size_t)PACK_BYTES + part_bytes;
    size_t need = sph_off + (size_t)N * 4 * sizeof(float);
    if (ws_size < need) return;
    _Float16* pack = (_Float16*)d_ws;
    float* part = (float*)((char*)d_ws + PACK_BYTES);
    float* sph  = (float*)((char*)d_ws + sph_off);
    float* outPot = (float*)d_out;
    float* outAcc = outPot + N;

    pack_weights<<<(110592 + 255) / 256, 256, 0, stream>>>(dpWh, icWh, dpWin, icWin,
                                                           dpWout, icWout, pack);
    sph_prep<<<(N + 255) / 256, 256, 0, stream>>>(tx, sph, N);

    (void)hipFuncSetAttribute(reinterpret_cast<const void*>(node_main),
                              hipFuncAttributeMaxDynamicSharedMemorySize, SMEM_BYTES);
    node_main<<<512, 256, SMEM_BYTES, stream>>>(sph,
        dpBin, dpBh, icBin, icBh, dpWin, icWin,
        pack, part, N);

    node_combine<<<(N + 255) / 256, 256, 0, stream>>>(tx, part, dpBout, icBout,
                                                      outPot, outAcc, N);
}

// Round 17
// 271.469 us; speedup vs baseline: 1.5282x; 1.0450x over previous
//
#include <hip/hip_runtime.h>

typedef _Float16 v8h __attribute__((ext_vector_type(8)));
typedef _Float16 v4h __attribute__((ext_vector_type(4)));
typedef float    v4f __attribute__((ext_vector_type(4)));

template<int V> struct IC { static constexpr int value = V; };

__device__ __forceinline__ float fast_tanh(float x) {
    float e = __expf(2.0f * x);
    return 1.0f - 2.0f * __builtin_amdgcn_rcpf(e + 1.0f);
}

// ---------------------------------------------------------------------------
// pack layout (halves):
//  FWD hidden:  idx = ((((pipe*3+l)*8 + nt)*4 + kk)*64 + lane)*8 + j   [0, 98304)
//               val = Wh[l][k = kk*32 + (lane>>4)*8 + j][n = nt*16 + (lane&15)]
//  BWD hidden (transposed A-frags):  98304 + same indexing             [98304, 196608)
//               val = Wh[l][f = nt*16 + (lane&15)][g = kk*32 + (lane>>4)*8 + j]
//  GRADWIN:     196608 + ((pipe*4 + kk)*64 + lane)*8 + j               [196608, 200704)
//               m=lane&15 (<3), k=kk*32+(lane>>4)*8+j
//               dp: dpWin[(m+1)*128+k] (rows r,th,ph); ic: icWin[m*128+k]
// ---------------------------------------------------------------------------
__global__ void pack_weights(const float* __restrict__ dpWh,
                             const float* __restrict__ icWh,
                             const float* __restrict__ dpWin,
                             const float* __restrict__ icWin,
                             _Float16* __restrict__ out) {
    int idx = blockIdx.x * 256 + threadIdx.x;
    if (idx < 98304) {
        int j    = idx & 7;
        int lane = (idx >> 3) & 63;
        int kk   = (idx >> 9) & 3;
        int nt   = (idx >> 11) & 7;
        int lp   = idx >> 14;           // 0..5
        int l    = lp % 3;
        const float* src = (lp >= 3) ? icWh : dpWh;
        int k = kk * 32 + (lane >> 4) * 8 + j;
        int n = nt * 16 + (lane & 15);
        out[idx] = (_Float16)src[(l * 128 + k) * 128 + n];
    } else if (idx < 196608) {
        int f    = idx - 98304;
        int j    = f & 7;
        int lane = (f >> 3) & 63;
        int kk   = (f >> 9) & 3;
        int nt   = (f >> 11) & 7;
        int lp   = f >> 14;
        int l    = lp % 3;
        const float* src = (lp >= 3) ? icWh : dpWh;
        int fr = nt * 16 + (lane & 15);
        int g  = kk * 32 + (lane >> 4) * 8 + j;
        out[idx] = (_Float16)src[(l * 128 + fr) * 128 + g];
    } else if (idx < 200704) {
        int f    = idx - 196608;
        int j    = f & 7;
        int lane = (f >> 3) & 63;
        int kk   = (f >> 9) & 3;
        int pipe = (f >> 11) & 1;
        int m = lane & 15;
        int k = kk * 32 + (lane >> 4) * 8 + j;
        float v = 0.0f;
        if (m < 3) v = pipe ? icWin[m * 128 + k] : dpWin[(m + 1) * 128 + k];
        out[idx] = (_Float16)v;
    }
}

__global__ void sph_prep(const float* __restrict__ tx, float* __restrict__ sph, int N) {
    int row = blockIdx.x * 256 + threadIdx.x;
    if (row >= N) return;
    float4 q = ((const float4*)tx)[row];
    float x = q.y, y = q.z, z = q.w;
    float r  = sqrtf(x * x + y * y + z * z + 1e-12f);
    float uc = fminf(1.0f, fmaxf(-1.0f, z / r));
    ((float4*)sph)[row] = make_float4(q.x, r, acosf(uc), atan2f(y, x));
}

// LDS per block (53248 B -> >=2 blocks/CU):
//   H0,H1,H2  : 3 x 32 rows x ROWH halves (forward activations h1..h3)
//   GA,GB     : gamma ping-pong
//   btab      : f32[8][128], winb : f32[8][128], woutb : f32[2][128]
//   vbuf      : f32[4][32] per-wave V partials
#define ROWH 136
#define HBYTES 8704
#define SMEM_BYTES 53248
#define PACK_BYTES 401408   // 200704 halves

__launch_bounds__(256, 2)
__global__ void node_main(const float* __restrict__ sph,
                          const float* __restrict__ dpBin, const float* __restrict__ dpBh,
                          const float* __restrict__ icBin, const float* __restrict__ icBh,
                          const float* __restrict__ dpWin, const float* __restrict__ icWin,
                          const float* __restrict__ dpWout, const float* __restrict__ icWout,
                          const _Float16* __restrict__ pack,
                          float* __restrict__ part, int N)
{
    extern __shared__ char smem[];
    _Float16* H0 = (_Float16*)smem;
    _Float16* H1 = (_Float16*)(smem + HBYTES);
    _Float16* H2 = (_Float16*)(smem + 2 * HBYTES);
    _Float16* GA = (_Float16*)(smem + 3 * HBYTES);
    _Float16* GB = (_Float16*)(smem + 4 * HBYTES);
    float* btab  = (float*)(smem + 5 * HBYTES);
    float* winb  = (float*)(smem + 5 * HBYTES + 4096);
    float* woutb = (float*)(smem + 5 * HBYTES + 8192);
    float* vbuf  = (float*)(smem + 5 * HBYTES + 9216);

    const int tid  = threadIdx.x;
    const int wave = tid >> 6;          // 0..3 = 32-feature slice cg
    const int lane = tid & 63;
    const int l15  = lane & 15;
    const int s    = lane >> 4;
    const int cg   = wave;
    const int fb   = cg * 32 + s * 4;   // C-row feature base (subslice 0)
    const int f8   = cg * 32 + s * 8;   // L0: 8 features/thread

    for (int i = tid; i < 1024; i += 256) {
        int row = i >> 7, col = i & 127;
        float bv, wv;
        if      (row == 0) bv = dpBin[col];
        else if (row <  4) bv = dpBh[(row - 1) * 128 + col];
        else if (row == 4) bv = icBin[col];
        else               bv = icBh[(row - 5) * 128 + col];
        if      (row <  4) wv = dpWin[row * 128 + col];
        else if (row <  7) wv = icWin[(row - 4) * 128 + col];
        else               wv = 0.0f;
        btab[i] = bv;
        winb[i] = wv;
    }
    woutb[tid] = (tid < 128) ? dpWout[tid] : icWout[tid - 128];

    // persistent dp FORWARD weights for my 32-feature slice (96 regs)
    v8h wreg[3][2][4];
    #pragma unroll
    for (int L = 0; L < 3; L++)
        #pragma unroll
        for (int n2 = 0; n2 < 2; n2++)
            #pragma unroll
            for (int kk = 0; kk < 4; kk++)
                wreg[L][n2][kk] = *(const v8h*)(pack + (((L * 8 + cg * 2 + n2) * 4 + kk) << 9) + (lane << 3));
    __syncthreads();

    // static bases
    const int rdo = l15 * ROWH + s * 8;        // B-frag read offset
    const int epo = l15 * ROWH + fb;           // epilogue / h-read offset
    const float NP0 = 1.0f - 0.7745966692414834f;
    const float NP2 = 1.0f + 0.7745966692414834f;

    const int nun = (((N + 31) >> 5) << 2);
    for (int u = blockIdx.x; u < nun; u += gridDim.x) {
        const int chunk = u >> 2;
        const int set   = u & 3;
        const bool isic = (set == 3);
        const int boff  = isic ? 512 : 0;

        // ---- L0: h1 = tanh(Win x + b), 32 rows x my 8 feats ----
        {
            v4f w0a = *(const v4f*)(winb + boff + f8),       w0b = *(const v4f*)(winb + boff + f8 + 4);
            v4f w1a = *(const v4f*)(winb + boff + 128 + f8), w1b = *(const v4f*)(winb + boff + 128 + f8 + 4);
            v4f w2a = *(const v4f*)(winb + boff + 256 + f8), w2b = *(const v4f*)(winb + boff + 256 + f8 + 4);
            v4f w3a = *(const v4f*)(winb + boff + 384 + f8), w3b = *(const v4f*)(winb + boff + 384 + f8 + 4);
            float np1 = (set == 0) ? NP0 : ((set == 1) ? 1.0f : NP2);
            #pragma unroll
            for (int q = 0; q < 2; q++) {
                int row = chunk * 32 + q * 16 + l15;
                float4 sp = (row < N) ? ((const float4*)sph)[row] : make_float4(0.f, 1.f, 1.f, 1.f);
                float i0, i1, i2, i3;
                if (isic) { i0 = sp.y; i1 = sp.z; i2 = sp.w; i3 = 0.0f; }
                else      { i0 = 0.5f * sp.x * np1; i1 = sp.y; i2 = sp.z; i3 = sp.w; }
                v4f pa = *(const v4f*)(btab + boff + f8);
                v4f pb = *(const v4f*)(btab + boff + f8 + 4);
                #pragma unroll
                for (int j = 0; j < 4; j++) {
                    pa[j] += i0 * w0a[j] + i1 * w1a[j] + i2 * w2a[j] + i3 * w3a[j];
                    pb[j] += i0 * w0b[j] + i1 * w1b[j] + i2 * w2b[j] + i3 * w3b[j];
                }
                v8h hh;
                #pragma unroll
                for (int j = 0; j < 4; j++) {
                    hh[j]     = (_Float16)fast_tanh(pa[j]);
                    hh[4 + j] = (_Float16)fast_tanh(pb[j]);
                }
                *(v8h*)(H0 + (q * 16 + l15) * ROWH + f8) = hh;
            }
        }
        __syncthreads();                               // h1 ready

        // ---- forward hidden layer (tanh epilogue) ----
        auto fwd = [&](auto Lc, const _Float16* hin, _Float16* hout) {
            constexpr int L = decltype(Lc)::value;     // 1 or 2: h_L -> h_{L+1}
            v8h icwf[2][4];
            if (isic) {
                #pragma unroll
                for (int n2 = 0; n2 < 2; n2++)
                    #pragma unroll
                    for (int kk = 0; kk < 4; kk++)
                        icwf[n2][kk] = *(const v8h*)(pack + ((((3 + (L - 1)) * 8 + cg * 2 + n2) * 4 + kk) << 9) + (lane << 3));
            }
            const float* br = btab + boff + L * 128;
            #pragma unroll
            for (int t = 0; t < 2; t++) {
                const _Float16* rb = hin + rdo + t * (16 * ROWH);
                v8h b0 = *(const v8h*)(rb);
                v8h b1 = *(const v8h*)(rb + 32);
                v8h b2 = *(const v8h*)(rb + 64);
                v8h b3 = *(const v8h*)(rb + 96);
                #pragma unroll
                for (int n2 = 0; n2 < 2; n2++) {
                    const v8h* W = isic ? icwf[n2] : wreg[L - 1][n2];
                    v4f acc = *(const v4f*)(br + fb + n2 * 16);
                    acc = __builtin_amdgcn_mfma_f32_16x16x32_f16(W[0], b0, acc, 0, 0, 0);
                    acc = __builtin_amdgcn_mfma_f32_16x16x32_f16(W[1], b1, acc, 0, 0, 0);
                    acc = __builtin_amdgcn_mfma_f32_16x16x32_f16(W[2], b2, acc, 0, 0, 0);
                    acc = __builtin_amdgcn_mfma_f32_16x16x32_f16(W[3], b3, acc, 0, 0, 0);
                    v4h w = {(_Float16)fast_tanh(acc[0]), (_Float16)fast_tanh(acc[1]),
                             (_Float16)fast_tanh(acc[2]), (_Float16)fast_tanh(acc[3])};
                    *(v4h*)(hout + epo + n2 * 16 + t * (16 * ROWH)) = w;
                }
            }
        };

        fwd(IC<1>{}, H0, H1); __syncthreads();         // h2
        fwd(IC<2>{}, H1, H2); __syncthreads();         // h3

        // ---- fwd3: h4 transient -> V partials + gamma4 = (1-h4^2) .* wout ----
        {
            v8h icwf[2][4];
            if (isic) {
                #pragma unroll
                for (int n2 = 0; n2 < 2; n2++)
                    #pragma unroll
                    for (int kk = 0; kk < 4; kk++)
                        icwf[n2][kk] = *(const v8h*)(pack + (((5 * 8 + cg * 2 + n2) * 4 + kk) << 9) + (lane << 3));
            }
            const float* br = btab + boff + 384;
            const float* wo = woutb + (isic ? 128 : 0);
            float vp[2] = {0.0f, 0.0f};
            #pragma unroll
            for (int t = 0; t < 2; t++) {
                const _Float16* rb = H2 + rdo + t * (16 * ROWH);
                v8h b0 = *(const v8h*)(rb);
                v8h b1 = *(const v8h*)(rb + 32);
                v8h b2 = *(const v8h*)(rb + 64);
                v8h b3 = *(const v8h*)(rb + 96);
                #pragma unroll
                for (int n2 = 0; n2 < 2; n2++) {
                    const v8h* W = isic ? icwf[n2] : wreg[2][n2];
                    v4f acc = *(const v4f*)(br + fb + n2 * 16);
                    acc = __builtin_amdgcn_mfma_f32_16x16x32_f16(W[0], b0, acc, 0, 0, 0);
                    acc = __builtin_amdgcn_mfma_f32_16x16x32_f16(W[1], b1, acc, 0, 0, 0);
                    acc = __builtin_amdgcn_mfma_f32_16x16x32_f16(W[2], b2, acc, 0, 0, 0);
                    acc = __builtin_amdgcn_mfma_f32_16x16x32_f16(W[3], b3, acc, 0, 0, 0);
                    v4f wv = *(const v4f*)(wo + fb + n2 * 16);
                    float h0 = fast_tanh(acc[0]), h1 = fast_tanh(acc[1]);
                    float h2 = fast_tanh(acc[2]), h3 = fast_tanh(acc[3]);
                    vp[t] += h0 * wv[0] + h1 * wv[1] + h2 * wv[2] + h3 * wv[3];
                    v4h g = {(_Float16)((1.0f - h0 * h0) * wv[0]),
                             (_Float16)((1.0f - h1 * h1) * wv[1]),
                             (_Float16)((1.0f - h2 * h2) * wv[2]),
                             (_Float16)((1.0f - h3 * h3) * wv[3])};
                    *(v4h*)(GA + epo + n2 * 16 + t * (16 * ROWH)) = g;
                }
            }
            #pragma unroll
            for (int t = 0; t < 2; t++) {
                float v = vp[t];
                v += __shfl_xor(v, 16);
                v += __shfl_xor(v, 32);
                if (lane < 16) vbuf[wave * 32 + t * 16 + lane] = v;
            }
        }
        __syncthreads();                               // gamma4 + vbuf ready

        // ---- backward layer: gamma_{L} = D_L .* (W_L^T gamma_{L+1}) ----
        auto bwd = [&](auto Lc, const _Float16* gin, const _Float16* hsrc, _Float16* gout) {
            constexpr int L = decltype(Lc)::value;     // uses Wh[L-1]^T, D from h_L
            const int pipe3 = isic ? 3 : 0;
            v8h wT[2][4];
            #pragma unroll
            for (int n2 = 0; n2 < 2; n2++)
                #pragma unroll
                for (int kk = 0; kk < 4; kk++)
                    wT[n2][kk] = *(const v8h*)(pack + 98304 + ((((pipe3 + (L - 1)) * 8 + cg * 2 + n2) * 4 + kk) << 9) + (lane << 3));
            #pragma unroll
            for (int t = 0; t < 2; t++) {
                const _Float16* rb = gin + rdo + t * (16 * ROWH);
                v8h b0 = *(const v8h*)(rb);
                v8h b1 = *(const v8h*)(rb + 32);
                v8h b2 = *(const v8h*)(rb + 64);
                v8h b3 = *(const v8h*)(rb + 96);
                #pragma unroll
                for (int n2 = 0; n2 < 2; n2++) {
                    v4f acc = {0.f, 0.f, 0.f, 0.f};
                    acc = __builtin_amdgcn_mfma_f32_16x16x32_f16(wT[n2][0], b0, acc, 0, 0, 0);
                    acc = __builtin_amdgcn_mfma_f32_16x16x32_f16(wT[n2][1], b1, acc, 0, 0, 0);
                    acc = __builtin_amdgcn_mfma_f32_16x16x32_f16(wT[n2][2], b2, acc, 0, 0, 0);
                    acc = __builtin_amdgcn_mfma_f32_16x16x32_f16(wT[n2][3], b3, acc, 0, 0, 0);
                    v4h hv = *(const v4h*)(hsrc + epo + n2 * 16 + t * (16 * ROWH));
                    float h0 = (float)hv[0], h1 = (float)hv[1];
                    float h2 = (float)hv[2], h3 = (float)hv[3];
                    v4h g = {(_Float16)((1.0f - h0 * h0) * acc[0]),
                             (_Float16)((1.0f - h1 * h1) * acc[1]),
                             (_Float16)((1.0f - h2 * h2) * acc[2]),
                             (_Float16)((1.0f - h3 * h3) * acc[3])};
                    *(v4h*)(gout + epo + n2 * 16 + t * (16 * ROWH)) = g;
                }
            }
        };

        bwd(IC<3>{}, GA, H2, GB); __syncthreads();     // gamma3
        bwd(IC<2>{}, GB, H1, GA); __syncthreads();     // gamma2
        bwd(IC<1>{}, GA, H0, GB); __syncthreads();     // gamma1

        // ---- grad: (g_r,g_th,g_ph) = WinSel^T gamma1 ; V from vbuf ----
        {
            float* pbase = part + chunk * 512 + set * 128;
            if (wave < 2) {
                const int t = wave;
                v8h gw[4];
                #pragma unroll
                for (int kk = 0; kk < 4; kk++)
                    gw[kk] = *(const v8h*)(pack + 196608 + ((((isic ? 1 : 0) * 4 + kk)) << 9) + (lane << 3));
                const _Float16* rb = GB + rdo + t * (16 * ROWH);
                v4f acc = {0.f, 0.f, 0.f, 0.f};
                acc = __builtin_amdgcn_mfma_f32_16x16x32_f16(gw[0], *(const v8h*)(rb),      acc, 0, 0, 0);
                acc = __builtin_amdgcn_mfma_f32_16x16x32_f16(gw[1], *(const v8h*)(rb + 32), acc, 0, 0, 0);
                acc = __builtin_amdgcn_mfma_f32_16x16x32_f16(gw[2], *(const v8h*)(rb + 64), acc, 0, 0, 0);
                acc = __builtin_amdgcn_mfma_f32_16x16x32_f16(gw[3], *(const v8h*)(rb + 96), acc, 0, 0, 0);
                if (lane < 16) {
                    int rr = t * 16 + lane;
                    pbase[32 + rr] = acc[0];
                    pbase[64 + rr] = acc[1];
                    pbase[96 + rr] = acc[2];
                }
            } else if (wave == 2 && lane < 32) {
                pbase[lane] = vbuf[lane] + vbuf[32 + lane] + vbuf[64 + lane] + vbuf[96 + lane];
            }
        }
        // no trailing barrier: next L0 writes H0 (last read pre-bar by bwd1);
        // grad reads GB/vbuf, rewritten >=4 barriers later.
    }
}

// combine: quadrature + envelope + chain rule (exact f32 math as r15/16)
__global__ void node_combine(const float* __restrict__ tx, const float* __restrict__ part,
                             const float* __restrict__ dpBout, const float* __restrict__ icBout,
                             float* __restrict__ outPot, float* __restrict__ outAcc, int N)
{
    int row = blockIdx.x * 256 + threadIdx.x;
    if (row >= N) return;
    float4 q = ((const float4*)tx)[row];
    float t = q.x, x = q.y, y = q.z, z = q.w;
    float r  = sqrtf(x * x + y * y + z * z + 1e-12f);
    float rinv = 1.0f / r;
    float uc = fminf(1.0f, fmaxf(-1.0f, z * rinv));
    float rinv3 = rinv * rinv * rinv;
    float dacos = -1.0f / sqrtf(fmaxf(1.0f - uc * uc, 1e-30f));
    float dthx = dacos * (-x * z * rinv3);
    float dthy = dacos * (-y * z * rinv3);
    float dthz = dacos * (rinv - z * z * rinv3);
    float rho2 = fmaxf(x * x + y * y, 1e-30f);
    float dphx = -y / rho2;
    float dphy =  x / rho2;
    float opr  = 1.0f + r;
    float sEnv = -1.0f / opr;
    float dsdr =  1.0f / (opr * opr);
    float den  = r * r + 0.1f;
    float isq  = 1.0f / sqrtf(den);
    float Aan  = -isq;
    float dAdr = r * isq * isq * isq;

    const float* pr = part + ((row >> 5) * 512) + (row & 31);
    const float wq0 = 0.5555555555555556f, wq1 = 0.8888888888888889f, wq2 = 0.5555555555555556f;
    float dsum = wq0 * pr[0]       + wq1 * pr[128]      + wq2 * pr[256];
    float ds1  = wq0 * pr[32]      + wq1 * pr[128 + 32] + wq2 * pr[256 + 32];
    float ds2  = wq0 * pr[64]      + wq1 * pr[128 + 64] + wq2 * pr[256 + 64];
    float ds3  = wq0 * pr[96]      + wq1 * pr[128 + 96] + wq2 * pr[256 + 96];
    float vic = pr[384], g1 = pr[384 + 32], g2 = pr[384 + 64], g3 = pr[384 + 96];

    float ah = 0.5f * t;
    float tcv  = (vic + icBout[0]) + ah * (dsum + 2.0f * dpBout[0]);
    float dtcr = g1 + ah * ds1;
    float dtct = g2 + ah * ds2;
    float dtcp = g3 + ah * ds3;
    float pot = tcv * sEnv + Aan;
    float gx0 = sEnv * dtcr + tcv * dsdr + dAdr;
    float gx1 = sEnv * dtct;
    float gx2 = sEnv * dtcp;
    float ax = -(gx0 * (x * rinv) + gx1 * dthx + gx2 * dphx);
    float ay = -(gx0 * (y * rinv) + gx1 * dthy + gx2 * dphy);
    float az = -(gx0 * (z * rinv) + gx1 * dthz);
    outPot[row] = pot;
    outAcc[row * 3 + 0] = ax;
    outAcc[row * 3 + 1] = ay;
    outAcc[row * 3 + 2] = az;
}

extern "C" void kernel_launch(void* const* d_in, const int* in_sizes, int n_in,
                              void* d_out, int out_size, void* d_ws, size_t ws_size,
                              hipStream_t stream) {
    (void)n_in; (void)out_size;
    const float* tx     = (const float*)d_in[0];
    const float* dpWin  = (const float*)d_in[1];
    const float* dpBin  = (const float*)d_in[2];
    const float* dpWh   = (const float*)d_in[3];
    const float* dpBh   = (const float*)d_in[4];
    const float* dpWout = (const float*)d_in[5];
    const float* dpBout = (const float*)d_in[6];
    const float* icWin  = (const float*)d_in[7];
    const float* icBin  = (const float*)d_in[8];
    const float* icWh   = (const float*)d_in[9];
    const float* icBh   = (const float*)d_in[10];
    const float* icWout = (const float*)d_in[11];
    const float* icBout = (const float*)d_in[12];

    int N = in_sizes[0] / 4;
    int chunks = (N + 31) >> 5;
    size_t part_bytes = (size_t)chunks * 512 * sizeof(float);
    size_t sph_off = (size_t)PACK_BYTES + part_bytes;
    size_t need = sph_off + (size_t)N * 4 * sizeof(float);
    if (ws_size < need) return;
    _Float16* pack = (_Float16*)d_ws;
    float* part = (float*)((char*)d_ws + PACK_BYTES);
    float* sph  = (float*)((char*)d_ws + sph_off);
    float* outPot = (float*)d_out;
    float* outAcc = outPot + N;

    pack_weights<<<(200704 + 255) / 256, 256, 0, stream>>>(dpWh, icWh, dpWin, icWin, pack);
    sph_prep<<<(N + 255) / 256, 256, 0, stream>>>(tx, sph, N);

    (void)hipFuncSetAttribute(reinterpret_cast<const void*>(node_main),
                              hipFuncAttributeMaxDynamicSharedMemorySize, SMEM_BYTES);
    node_main<<<768, 256, SMEM_BYTES, stream>>>(sph,
        dpBin, dpBh, icBin, icBh, dpWin, icWin, dpWout, icWout,
        pack, part, N);

    node_combine<<<(N + 255) / 256, 256, 0, stream>>>(tx, part, dpBout, icBout,
                                                      outPot, outAcc, N);
}

// Round 18
// 224.581 us; speedup vs baseline: 1.8472x; 1.2088x over previous
//
#include <hip/hip_runtime.h>

typedef _Float16 v8h __attribute__((ext_vector_type(8)));
typedef _Float16 v4h __attribute__((ext_vector_type(4)));
typedef float    v4f __attribute__((ext_vector_type(4)));

template<int V> struct IC { static constexpr int value = V; };

__device__ __forceinline__ float fast_tanh(float x) {
    float e = __expf(2.0f * x);
    return 1.0f - 2.0f * __builtin_amdgcn_rcpf(e + 1.0f);
}

// ---------------------------------------------------------------------------
// pack layout (halves):
//  FWD hidden:  idx = ((((pipe*3+l)*8 + nt)*4 + kk)*64 + lane)*8 + j   [0, 98304)
//               val = Wh[l][k = kk*32 + (lane>>4)*8 + j][n = nt*16 + (lane&15)]
//  BWD hidden (transposed A-frags):  98304 + same indexing             [98304, 196608)
//               val = Wh[l][f = nt*16 + (lane&15)][g = kk*32 + (lane>>4)*8 + j]
//  GRADWIN:     196608 + ((pipe*4 + kk)*64 + lane)*8 + j               [196608, 200704)
// ---------------------------------------------------------------------------
__global__ void pack_weights(const float* __restrict__ dpWh,
                             const float* __restrict__ icWh,
                             const float* __restrict__ dpWin,
                             const float* __restrict__ icWin,
                             _Float16* __restrict__ out) {
    int idx = blockIdx.x * 256 + threadIdx.x;
    if (idx < 98304) {
        int j    = idx & 7;
        int lane = (idx >> 3) & 63;
        int kk   = (idx >> 9) & 3;
        int nt   = (idx >> 11) & 7;
        int lp   = idx >> 14;           // 0..5
        int l    = lp % 3;
        const float* src = (lp >= 3) ? icWh : dpWh;
        int k = kk * 32 + (lane >> 4) * 8 + j;
        int n = nt * 16 + (lane & 15);
        out[idx] = (_Float16)src[(l * 128 + k) * 128 + n];
    } else if (idx < 196608) {
        int f    = idx - 98304;
        int j    = f & 7;
        int lane = (f >> 3) & 63;
        int kk   = (f >> 9) & 3;
        int nt   = (f >> 11) & 7;
        int lp   = f >> 14;
        int l    = lp % 3;
        const float* src = (lp >= 3) ? icWh : dpWh;
        int fr = nt * 16 + (lane & 15);
        int g  = kk * 32 + (lane >> 4) * 8 + j;
        out[idx] = (_Float16)src[(l * 128 + fr) * 128 + g];
    } else if (idx < 200704) {
        int f    = idx - 196608;
        int j    = f & 7;
        int lane = (f >> 3) & 63;
        int kk   = (f >> 9) & 3;
        int pipe = (f >> 11) & 1;
        int m = lane & 15;
        int k = kk * 32 + (lane >> 4) * 8 + j;
        float v = 0.0f;
        if (m < 3) v = pipe ? icWin[m * 128 + k] : dpWin[(m + 1) * 128 + k];
        out[idx] = (_Float16)v;
    }
}

__global__ void sph_prep(const float* __restrict__ tx, float* __restrict__ sph, int N) {
    int row = blockIdx.x * 256 + threadIdx.x;
    if (row >= N) return;
    float4 q = ((const float4*)tx)[row];
    float x = q.y, y = q.z, z = q.w;
    float r  = sqrtf(x * x + y * y + z * z + 1e-12f);
    float uc = fminf(1.0f, fmaxf(-1.0f, z / r));
    ((float4*)sph)[row] = make_float4(q.x, r, acosf(uc), atan2f(y, x));
}

// LDS per block (53248 B; 3 blocks/CU = 159744 <= 163840 when regs <= 170):
//   H0,H1,H2  : 3 x 32 rows x ROWH halves (forward activations h1..h3)
//   GA,GB     : gamma ping-pong
//   btab/winb/woutb/vbuf tables
#define ROWH 136
#define HBYTES 8704
#define SMEM_BYTES 53248
#define PACK_BYTES 401408   // 200704 halves

__launch_bounds__(256, 2)
__global__ void node_main(const float* __restrict__ sph,
                          const float* __restrict__ dpBin, const float* __restrict__ dpBh,
                          const float* __restrict__ icBin, const float* __restrict__ icBh,
                          const float* __restrict__ dpWin, const float* __restrict__ icWin,
                          const float* __restrict__ dpWout, const float* __restrict__ icWout,
                          const _Float16* __restrict__ pack,
                          float* __restrict__ part, int N)
{
    extern __shared__ char smem[];
    _Float16* H0 = (_Float16*)smem;
    _Float16* H1 = (_Float16*)(smem + HBYTES);
    _Float16* H2 = (_Float16*)(smem + 2 * HBYTES);
    _Float16* GA = (_Float16*)(smem + 3 * HBYTES);
    _Float16* GB = (_Float16*)(smem + 4 * HBYTES);
    float* btab  = (float*)(smem + 5 * HBYTES);
    float* winb  = (float*)(smem + 5 * HBYTES + 4096);
    float* woutb = (float*)(smem + 5 * HBYTES + 8192);
    float* vbuf  = (float*)(smem + 5 * HBYTES + 9216);

    const int tid  = threadIdx.x;
    const int wave = tid >> 6;          // 0..3 = 32-feature slice cg
    const int lane = tid & 63;
    const int l15  = lane & 15;
    const int s    = lane >> 4;
    const int cg   = wave;
    const int fb   = cg * 32 + s * 4;   // C-row feature base (subslice 0)
    const int f8   = cg * 32 + s * 8;   // L0: 8 features/thread

    for (int i = tid; i < 1024; i += 256) {
        int row = i >> 7, col = i & 127;
        float bv, wv;
        if      (row == 0) bv = dpBin[col];
        else if (row <  4) bv = dpBh[(row - 1) * 128 + col];
        else if (row == 4) bv = icBin[col];
        else               bv = icBh[(row - 5) * 128 + col];
        if      (row <  4) wv = dpWin[row * 128 + col];
        else if (row <  7) wv = icWin[(row - 4) * 128 + col];
        else               wv = 0.0f;
        btab[i] = bv;
        winb[i] = wv;
    }
    woutb[tid] = (tid < 128) ? dpWout[tid] : icWout[tid - 128];
    __syncthreads();

    // static bases
    const int rdo = l15 * ROWH + s * 8;        // B-frag read offset
    const int epo = l15 * ROWH + fb;           // epilogue / h-read offset
    const float NP0 = 1.0f - 0.7745966692414834f;
    const float NP2 = 1.0f + 0.7745966692414834f;

    const int nun = (((N + 31) >> 5) << 2);
    for (int u = blockIdx.x; u < nun; u += gridDim.x) {
        const int chunk = u >> 2;
        const int set   = u & 3;
        const bool isic = (set == 3);
        const int boff  = isic ? 512 : 0;
        const int pipe3 = isic ? 3 : 0;

        // ---- L0: h1 = tanh(Win x + b), 32 rows x my 8 feats ----
        {
            v4f w0a = *(const v4f*)(winb + boff + f8),       w0b = *(const v4f*)(winb + boff + f8 + 4);
            v4f w1a = *(const v4f*)(winb + boff + 128 + f8), w1b = *(const v4f*)(winb + boff + 128 + f8 + 4);
            v4f w2a = *(const v4f*)(winb + boff + 256 + f8), w2b = *(const v4f*)(winb + boff + 256 + f8 + 4);
            v4f w3a = *(const v4f*)(winb + boff + 384 + f8), w3b = *(const v4f*)(winb + boff + 384 + f8 + 4);
            float np1 = (set == 0) ? NP0 : ((set == 1) ? 1.0f : NP2);
            #pragma unroll
            for (int q = 0; q < 2; q++) {
                int row = chunk * 32 + q * 16 + l15;
                float4 sp = (row < N) ? ((const float4*)sph)[row] : make_float4(0.f, 1.f, 1.f, 1.f);
                float i0, i1, i2, i3;
                if (isic) { i0 = sp.y; i1 = sp.z; i2 = sp.w; i3 = 0.0f; }
                else      { i0 = 0.5f * sp.x * np1; i1 = sp.y; i2 = sp.z; i3 = sp.w; }
                v4f pa = *(const v4f*)(btab + boff + f8);
                v4f pb = *(const v4f*)(btab + boff + f8 + 4);
                #pragma unroll
                for (int j = 0; j < 4; j++) {
                    pa[j] += i0 * w0a[j] + i1 * w1a[j] + i2 * w2a[j] + i3 * w3a[j];
                    pb[j] += i0 * w0b[j] + i1 * w1b[j] + i2 * w2b[j] + i3 * w3b[j];
                }
                v8h hh;
                #pragma unroll
                for (int j = 0; j < 4; j++) {
                    hh[j]     = (_Float16)fast_tanh(pa[j]);
                    hh[4 + j] = (_Float16)fast_tanh(pb[j]);
                }
                *(v8h*)(H0 + (q * 16 + l15) * ROWH + f8) = hh;
            }
        }
        __syncthreads();                               // h1 ready

        // ---- forward hidden layer (weights streamed from L2 per phase) ----
        auto fwd = [&](auto Lc, const _Float16* hin, _Float16* hout) {
            constexpr int L = decltype(Lc)::value;     // 1 or 2: h_L -> h_{L+1}
            const int lidx = pipe3 + (L - 1);
            v8h wf[2][4];
            #pragma unroll
            for (int n2 = 0; n2 < 2; n2++)
                #pragma unroll
                for (int kk = 0; kk < 4; kk++)
                    wf[n2][kk] = *(const v8h*)(pack + (((lidx * 8 + cg * 2 + n2) * 4 + kk) << 9) + (lane << 3));
            const float* br = btab + boff + L * 128;
            #pragma unroll
            for (int t = 0; t < 2; t++) {
                const _Float16* rb = hin + rdo + t * (16 * ROWH);
                v8h b0 = *(const v8h*)(rb);
                v8h b1 = *(const v8h*)(rb + 32);
                v8h b2 = *(const v8h*)(rb + 64);
                v8h b3 = *(const v8h*)(rb + 96);
                #pragma unroll
                for (int n2 = 0; n2 < 2; n2++) {
                    v4f acc = *(const v4f*)(br + fb + n2 * 16);
                    acc = __builtin_amdgcn_mfma_f32_16x16x32_f16(wf[n2][0], b0, acc, 0, 0, 0);
                    acc = __builtin_amdgcn_mfma_f32_16x16x32_f16(wf[n2][1], b1, acc, 0, 0, 0);
                    acc = __builtin_amdgcn_mfma_f32_16x16x32_f16(wf[n2][2], b2, acc, 0, 0, 0);
                    acc = __builtin_amdgcn_mfma_f32_16x16x32_f16(wf[n2][3], b3, acc, 0, 0, 0);
                    v4h w = {(_Float16)fast_tanh(acc[0]), (_Float16)fast_tanh(acc[1]),
                             (_Float16)fast_tanh(acc[2]), (_Float16)fast_tanh(acc[3])};
                    *(v4h*)(hout + epo + n2 * 16 + t * (16 * ROWH)) = w;
                }
            }
        };

        fwd(IC<1>{}, H0, H1); __syncthreads();         // h2
        fwd(IC<2>{}, H1, H2); __syncthreads();         // h3

        // ---- fwd3: h4 transient -> V partials + gamma4 = (1-h4^2) .* wout ----
        {
            const int lidx = pipe3 + 2;
            v8h wf[2][4];
            #pragma unroll
            for (int n2 = 0; n2 < 2; n2++)
                #pragma unroll
                for (int kk = 0; kk < 4; kk++)
                    wf[n2][kk] = *(const v8h*)(pack + (((lidx * 8 + cg * 2 + n2) * 4 + kk) << 9) + (lane << 3));
            const float* br = btab + boff + 384;
            const float* wo = woutb + (isic ? 128 : 0);
            float vp[2] = {0.0f, 0.0f};
            #pragma unroll
            for (int t = 0; t < 2; t++) {
                const _Float16* rb = H2 + rdo + t * (16 * ROWH);
                v8h b0 = *(const v8h*)(rb);
                v8h b1 = *(const v8h*)(rb + 32);
                v8h b2 = *(const v8h*)(rb + 64);
                v8h b3 = *(const v8h*)(rb + 96);
                #pragma unroll
                for (int n2 = 0; n2 < 2; n2++) {
                    v4f acc = *(const v4f*)(br + fb + n2 * 16);
                    acc = __builtin_amdgcn_mfma_f32_16x16x32_f16(wf[n2][0], b0, acc, 0, 0, 0);
                    acc = __builtin_amdgcn_mfma_f32_16x16x32_f16(wf[n2][1], b1, acc, 0, 0, 0);
                    acc = __builtin_amdgcn_mfma_f32_16x16x32_f16(wf[n2][2], b2, acc, 0, 0, 0);
                    acc = __builtin_amdgcn_mfma_f32_16x16x32_f16(wf[n2][3], b3, acc, 0, 0, 0);
                    v4f wv = *(const v4f*)(wo + fb + n2 * 16);
                    float h0 = fast_tanh(acc[0]), h1 = fast_tanh(acc[1]);
                    float h2 = fast_tanh(acc[2]), h3 = fast_tanh(acc[3]);
                    vp[t] += h0 * wv[0] + h1 * wv[1] + h2 * wv[2] + h3 * wv[3];
                    v4h g = {(_Float16)((1.0f - h0 * h0) * wv[0]),
                             (_Float16)((1.0f - h1 * h1) * wv[1]),
                             (_Float16)((1.0f - h2 * h2) * wv[2]),
                             (_Float16)((1.0f - h3 * h3) * wv[3])};
                    *(v4h*)(GA + epo + n2 * 16 + t * (16 * ROWH)) = g;
                }
            }
            #pragma unroll
            for (int t = 0; t < 2; t++) {
                float v = vp[t];
                v += __shfl_xor(v, 16);
                v += __shfl_xor(v, 32);
                if (lane < 16) vbuf[wave * 32 + t * 16 + lane] = v;
            }
        }
        __syncthreads();                               // gamma4 + vbuf ready

        // ---- backward layer: gamma_{L} = D_L .* (W_L^T gamma_{L+1}) ----
        auto bwd = [&](auto Lc, const _Float16* gin, const _Float16* hsrc, _Float16* gout) {
            constexpr int L = decltype(Lc)::value;
            v8h wT[2][4];
            #pragma unroll
            for (int n2 = 0; n2 < 2; n2++)
                #pragma unroll
                for (int kk = 0; kk < 4; kk++)
                    wT[n2][kk] = *(const v8h*)(pack + 98304 + ((((pipe3 + (L - 1)) * 8 + cg * 2 + n2) * 4 + kk) << 9) + (lane << 3));
            #pragma unroll
            for (int t = 0; t < 2; t++) {
                const _Float16* rb = gin + rdo + t * (16 * ROWH);
                v8h b0 = *(const v8h*)(rb);
                v8h b1 = *(const v8h*)(rb + 32);
                v8h b2 = *(const v8h*)(rb + 64);
                v8h b3 = *(const v8h*)(rb + 96);
                #pragma unroll
                for (int n2 = 0; n2 < 2; n2++) {
                    v4f acc = {0.f, 0.f, 0.f, 0.f};
                    acc = __builtin_amdgcn_mfma_f32_16x16x32_f16(wT[n2][0], b0, acc, 0, 0, 0);
                    acc = __builtin_amdgcn_mfma_f32_16x16x32_f16(wT[n2][1], b1, acc, 0, 0, 0);
                    acc = __builtin_amdgcn_mfma_f32_16x16x32_f16(wT[n2][2], b2, acc, 0, 0, 0);
                    acc = __builtin_amdgcn_mfma_f32_16x16x32_f16(wT[n2][3], b3, acc, 0, 0, 0);
                    v4h hv = *(const v4h*)(hsrc + epo + n2 * 16 + t * (16 * ROWH));
                    float h0 = (float)hv[0], h1 = (float)hv[1];
                    float h2 = (float)hv[2], h3 = (float)hv[3];
                    v4h g = {(_Float16)((1.0f - h0 * h0) * acc[0]),
                             (_Float16)((1.0f - h1 * h1) * acc[1]),
                             (_Float16)((1.0f - h2 * h2) * acc[2]),
                             (_Float16)((1.0f - h3 * h3) * acc[3])};
                    *(v4h*)(gout + epo + n2 * 16 + t * (16 * ROWH)) = g;
                }
            }
        };

        bwd(IC<3>{}, GA, H2, GB); __syncthreads();     // gamma3
        bwd(IC<2>{}, GB, H1, GA); __syncthreads();     // gamma2
        bwd(IC<1>{}, GA, H0, GB); __syncthreads();     // gamma1

        // ---- grad: (g_r,g_th,g_ph) = WinSel^T gamma1 ; V from vbuf ----
        {
            float* pbase = part + chunk * 512 + set * 128;
            if (wave < 2) {
                const int t = wave;
                v8h gw[4];
                #pragma unroll
                for (int kk = 0; kk < 4; kk++)
                    gw[kk] = *(const v8h*)(pack + 196608 + ((((isic ? 1 : 0) * 4 + kk)) << 9) + (lane << 3));
                const _Float16* rb = GB + rdo + t * (16 * ROWH);
                v4f acc = {0.f, 0.f, 0.f, 0.f};
                acc = __builtin_amdgcn_mfma_f32_16x16x32_f16(gw[0], *(const v8h*)(rb),      acc, 0, 0, 0);
                acc = __builtin_amdgcn_mfma_f32_16x16x32_f16(gw[1], *(const v8h*)(rb + 32), acc, 0, 0, 0);
                acc = __builtin_amdgcn_mfma_f32_16x16x32_f16(gw[2], *(const v8h*)(rb + 64), acc, 0, 0, 0);
                acc = __builtin_amdgcn_mfma_f32_16x16x32_f16(gw[3], *(const v8h*)(rb + 96), acc, 0, 0, 0);
                if (lane < 16) {
                    int rr = t * 16 + lane;
                    pbase[32 + rr] = acc[0];
                    pbase[64 + rr] = acc[1];
                    pbase[96 + rr] = acc[2];
                }
            } else if (wave == 2 && lane < 32) {
                pbase[lane] = vbuf[lane] + vbuf[32 + lane] + vbuf[64 + lane] + vbuf[96 + lane];
            }
        }
        // no trailing barrier: next L0 writes only its own feature slice of H0
        // (same-wave), grad reads GB/vbuf rewritten >=4 barriers later.
    }
}

// combine: quadrature + envelope + chain rule (exact f32 math as r15-17)
__global__ void node_combine(const float* __restrict__ tx, const float* __restrict__ part,
                             const float* __restrict__ dpBout, const float* __restrict__ icBout,
                             float* __restrict__ outPot, float* __restrict__ outAcc, int N)
{
    int row = blockIdx.x * 256 + threadIdx.x;
    if (row >= N) return;
    float4 q = ((const float4*)tx)[row];
    float t = q.x, x = q.y, y = q.z, z = q.w;
    float r  = sqrtf(x * x + y * y + z * z + 1e-12f);
    float rinv = 1.0f / r;
    float uc = fminf(1.0f, fmaxf(-1.0f, z * rinv));
    float rinv3 = rinv * rinv * rinv;
    float dacos = -1.0f / sqrtf(fmaxf(1.0f - uc * uc, 1e-30f));
    float dthx = dacos * (-x * z * rinv3);
    float dthy = dacos * (-y * z * rinv3);
    float dthz = dacos * (rinv - z * z * rinv3);
    float rho2 = fmaxf(x * x + y * y, 1e-30f);
    float dphx = -y / rho2;
    float dphy =  x / rho2;
    float opr  = 1.0f + r;
    float sEnv = -1.0f / opr;
    float dsdr =  1.0f / (opr * opr);
    float den  = r * r + 0.1f;
    float isq  = 1.0f / sqrtf(den);
    float Aan  = -isq;
    float dAdr = r * isq * isq * isq;

    const float* pr = part + ((row >> 5) * 512) + (row & 31);
    const float wq0 = 0.5555555555555556f, wq1 = 0.8888888888888889f, wq2 = 0.5555555555555556f;
    float dsum = wq0 * pr[0]       + wq1 * pr[128]      + wq2 * pr[256];
    float ds1  = wq0 * pr[32]      + wq1 * pr[128 + 32] + wq2 * pr[256 + 32];
    float ds2  = wq0 * pr[64]      + wq1 * pr[128 + 64] + wq2 * pr[256 + 64];
    float ds3  = wq0 * pr[96]      + wq1 * pr[128 + 96] + wq2 * pr[256 + 96];
    float vic = pr[384], g1 = pr[384 + 32], g2 = pr[384 + 64], g3 = pr[384 + 96];

    float ah = 0.5f * t;
    float tcv  = (vic + icBout[0]) + ah * (dsum + 2.0f * dpBout[0]);
    float dtcr = g1 + ah * ds1;
    float dtct = g2 + ah * ds2;
    float dtcp = g3 + ah * ds3;
    float pot = tcv * sEnv + Aan;
    float gx0 = sEnv * dtcr + tcv * dsdr + dAdr;
    float gx1 = sEnv * dtct;
    float gx2 = sEnv * dtcp;
    float ax = -(gx0 * (x * rinv) + gx1 * dthx + gx2 * dphx);
    float ay = -(gx0 * (y * rinv) + gx1 * dthy + gx2 * dphy);
    float az = -(gx0 * (z * rinv) + gx1 * dthz);
    outPot[row] = pot;
    outAcc[row * 3 + 0] = ax;
    outAcc[row * 3 + 1] = ay;
    outAcc[row * 3 + 2] = az;
}

extern "C" void kernel_launch(void* const* d_in, const int* in_sizes, int n_in,
                              void* d_out, int out_size, void* d_ws, size_t ws_size,
                              hipStream_t stream) {
    (void)n_in; (void)out_size;
    const float* tx     = (const float*)d_in[0];
    const float* dpWin  = (const float*)d_in[1];
    const float* dpBin  = (const float*)d_in[2];
    const float* dpWh   = (const float*)d_in[3];
    const float* dpBh   = (const float*)d_in[4];
    const float* dpWout = (const float*)d_in[5];
    const float* dpBout = (const float*)d_in[6];
    const float* icWin  = (const float*)d_in[7];
    const float* icBin  = (const float*)d_in[8];
    const float* icWh   = (const float*)d_in[9];
    const float* icBh   = (const float*)d_in[10];
    const float* icWout = (const float*)d_in[11];
    const float* icBout = (const float*)d_in[12];

    int N = in_sizes[0] / 4;
    int chunks = (N + 31) >> 5;
    size_t part_bytes = (size_t)chunks * 512 * sizeof(float);
    size_t sph_off = (size_t)PACK_BYTES + part_bytes;
    size_t need = sph_off + (size_t)N * 4 * sizeof(float);
    if (ws_size < need) return;
    _Float16* pack = (_Float16*)d_ws;
    float* part = (float*)((char*)d_ws + PACK_BYTES);
    float* sph  = (float*)((char*)d_ws + sph_off);
    float* outPot = (float*)d_out;
    float* outAcc = outPot + N;

    pack_weights<<<(200704 + 255) / 256, 256, 0, stream>>>(dpWh, icWh, dpWin, icWin, pack);
    sph_prep<<<(N + 255) / 256, 256, 0, stream>>>(tx, sph, N);

    (void)hipFuncSetAttribute(reinterpret_cast<const void*>(node_main),
                              hipFuncAttributeMaxDynamicSharedMemorySize, SMEM_BYTES);
    node_main<<<768, 256, SMEM_BYTES, stream>>>(sph,
        dpBin, dpBh, icBin, icBh, dpWin, icWin, dpWout, icWout,
        pack, part, N);

    node_combine<<<(N + 255) / 256, 256, 0, stream>>>(tx, part, dpBout, icBout,
                                                      outPot, outAcc, N);
}